// Round 3
// baseline (279.236 us; speedup 1.0000x reference)
//
#include <hip/hip_runtime.h>
#include <cstdint>
#include <cstddef>

#define B_ 8
#define N_ 10000
#define C_ 64
#define DIM_ 256
#define E_ 160000
#define ROWS_ (B_ * N_)            // 80000
#define OUT_OFF_ ((size_t)B_ * N_ * C_)  // 5,120,000

typedef unsigned short u16;
typedef unsigned int u32;
typedef __attribute__((ext_vector_type(8))) short bf16x8;
typedef __attribute__((ext_vector_type(4))) float f32x4;

__device__ __forceinline__ u16 f2bf(float f) {
    unsigned int u = __float_as_uint(f);
    unsigned int r = u + 0x7FFF + ((u >> 16) & 1);  // RNE
    return (u16)(r >> 16);
}
__device__ __forceinline__ float bf2f(u32 h) {      // low 16 bits hold bf16
    return __uint_as_float(h << 16);
}
__device__ __forceinline__ unsigned int pack2(float a, float b) {
    return (unsigned int)f2bf(a) | ((unsigned int)f2bf(b) << 16);
}
__device__ __forceinline__ float swish_f(float v, float sp) {
    float e = __expf(-v * sp);
    float s = __builtin_amdgcn_rcpf(1.0f + e);
    return v * s * (1.0f / 1.1f);
}

#define MFMA16(a, b, c) __builtin_amdgcn_mfma_f32_16x16x32_bf16(a, b, c, 0, 0, 0)

// ---- graph preprocessing -------------------------------------------------

__global__ void k_deg(const int* __restrict__ dst, const float* __restrict__ ew,
                      float* __restrict__ deg, int* __restrict__ cnt) {
    int e = blockIdx.x * 256 + threadIdx.x;
    if (e < E_) {
        int d = dst[e];
        atomicAdd(&deg[d], ew[e]);
        atomicAdd(&cnt[d], 1);
    }
}

__global__ void k_dis(const float* __restrict__ deg, float* __restrict__ dis) {
    int n = blockIdx.x * 256 + threadIdx.x;
    if (n < N_) {
        float d = deg[n];
        dis[n] = d > 0.f ? rsqrtf(d) : 0.f;
    }
}

__global__ void k_scan(const int* __restrict__ cnt, int* __restrict__ offs,
                       int* __restrict__ cursor) {
    __shared__ int part[1024];
    int t = threadIdx.x;
    const int CH = 10;
    int base = t * CH;
    int s = 0;
    for (int i = 0; i < CH; i++) {
        int idx = base + i;
        if (idx < N_) s += cnt[idx];
    }
    part[t] = s;
    __syncthreads();
    for (int off = 1; off < 1024; off <<= 1) {
        int v = 0;
        if (t >= off) v = part[t - off];
        __syncthreads();
        if (t >= off) part[t] += v;
        __syncthreads();
    }
    int run = (t > 0) ? part[t - 1] : 0;
    for (int i = 0; i < CH; i++) {
        int idx = base + i;
        if (idx < N_) {
            offs[idx] = run;
            cursor[idx] = run;
            run += cnt[idx];
        }
    }
    if (t == 1023) offs[N_] = run;
}

__global__ void k_scatter(const int* __restrict__ src, const int* __restrict__ dst,
                          const float* __restrict__ ew, const float* __restrict__ dis,
                          int* __restrict__ cursor, int* __restrict__ ssrc,
                          float* __restrict__ sw) {
    int e = blockIdx.x * 256 + threadIdx.x;
    if (e < E_) {
        int sn = src[e], dn = dst[e];
        float w = -(dis[sn] * ew[e] * dis[dn]);
        int p = atomicAdd(&cursor[dn], 1);
        ssrc[p] = sn;
        sw[p] = w;
    }
}

// weight transpose to N-major bf16 + vectorized x cast
__global__ void k_prepw(const float* __restrict__ Wc, const float* __restrict__ W1,
                        const float* __restrict__ W2, const float* __restrict__ x,
                        u16* __restrict__ Wct, u16* __restrict__ W1t,
                        u16* __restrict__ W2t, u16* __restrict__ xbf) {
    int i = blockIdx.x * 256 + threadIdx.x;
    if (i < 49152) {
        int nr = i / 192, k = i % 192;
        Wct[i] = f2bf(Wc[k * 256 + nr]);
    } else if (i < 114688) {
        int j = i - 49152;
        int nr = j >> 8, k = j & 255;
        W1t[j] = f2bf(W1[k * 256 + nr]);
    } else if (i < 131072) {
        int j = i - 114688;
        int nr = j >> 8, k = j & 255;
        W2t[j] = f2bf(W2[k * 64 + nr]);
    } else {
        int j = i - 131072;
        if (j < (B_ * N_ * C_) / 4) {
            float4 v = ((const float4*)x)[j];
            uint2 pv = {pack2(v.x, v.y), pack2(v.z, v.w)};
            ((uint2*)xbf)[j] = pv;
        }
    }
}

// bf16 gather SpMM. One wave per (batch, node); XCD-batch swizzle (b = blk&7).
// mode==1: O = 2*sum - xin  (fused Tx2 computation)
__global__ __launch_bounds__(256) void k_prop(
        const u16* __restrict__ T, const int* __restrict__ offs,
        const int* __restrict__ ssrc, const float* __restrict__ sw,
        const u16* __restrict__ xin, u16* __restrict__ O, int mode) {
    int w = __builtin_amdgcn_readfirstlane(threadIdx.x >> 6);
    int lane = threadIdx.x & 63;
    int b = blockIdx.x & 7;
    int nb = blockIdx.x >> 3;
    int n = nb * 4 + w;
    const u16* Tb = T + (size_t)b * (N_ * C_);
    int s = offs[n], e = offs[n + 1];
    float sum = 0.f;
    int j = s;
    for (; j < e && (j & 3); ++j) sum += bf2f(Tb[(size_t)ssrc[j] * 64 + lane]) * sw[j];
    for (; j + 4 <= e; j += 4) {
        int4 idx = *(const int4*)&ssrc[j];
        float4 wv = *(const float4*)&sw[j];
        sum += bf2f(Tb[(size_t)idx.x * 64 + lane]) * wv.x
             + bf2f(Tb[(size_t)idx.y * 64 + lane]) * wv.y
             + bf2f(Tb[(size_t)idx.z * 64 + lane]) * wv.z
             + bf2f(Tb[(size_t)idx.w * 64 + lane]) * wv.w;
    }
    for (; j < e; ++j) sum += bf2f(Tb[(size_t)ssrc[j] * 64 + lane]) * sw[j];
    size_t g = ((size_t)b * N_ + n) * 64 + lane;
    float v = sum;
    if (mode == 1) v = 2.f * sum - bf2f(xin[g]);
    O[g] = f2bf(v);
}

// ---- fused cheb-einsum + MLP, bf16 MFMA, M=64 rows/block -----------------
// 256 threads (4 waves); wave w owns a 64-col slice (16-col for GEMM3).
// R3 change: SINGLE LDS buffer (33.8 KB) sequentially reused A0 -> h -> h2
// (acc lives in registers across each transition; 5 barriers). LDS 67.6->33.8KB
// doubles blocks/CU to 4 -> 16 waves/CU of INDEPENDENT blocks that desync
// phases (R1 showed same-block waves stall together; R2 showed the stall is
// a latency chain). VGPR must stay <=128 for the 16-wave tier (was 88).
__global__ __launch_bounds__(256, 4) void k_fused(
        const float* __restrict__ x, const u16* __restrict__ xbf,
        const u16* __restrict__ Tx1, const u16* __restrict__ Tx2,
        const u16* __restrict__ Wct, const float* __restrict__ bc,
        const u16* __restrict__ W1t, const float* __restrict__ b1,
        const u16* __restrict__ W2t, const float* __restrict__ b2,
        const float* __restrict__ beta, float* __restrict__ out) {
    __shared__ u16 buf[64 * 264];   // A0 (cols 0..191) -> h (0..255) -> h2
    int t = threadIdx.x;

    // stage A0 = [xbf | Tx1 | Tx2] bf16, row-major, K-stride 264
    {
        size_t base = (size_t)blockIdx.x * 1024;  // uint2 units (64 rows x 16)
        const uint2* xb = (const uint2*)xbf + base;
        const uint2* tb = (const uint2*)Tx1 + base;
        const uint2* pb = (const uint2*)Tx2 + base;
#pragma unroll
        for (int rep = 0; rep < 4; ++rep) {
            int p = t + rep * 256;
            int r = p >> 4, c4 = p & 15;
            *(uint2*)&buf[r * 264 + c4 * 4] = xb[p];
            *(uint2*)&buf[r * 264 + 64 + c4 * 4] = tb[p];
            *(uint2*)&buf[r * 264 + 128 + c4 * 4] = pb[p];
        }
    }
    __syncthreads();

    float sp = logf(1.f + expf(beta[0]));
    int lane = t & 63, w = t >> 6;
    int m = lane & 15, quad = lane >> 4;
    int q8 = quad * 8;

    // ---- GEMM1: h = A0[64x192] @ Wc[192x256], +bc, swish (regs -> buf)
    {
        f32x4 acc[4][4] = {};
        bf16x8 bfr[4][4];   // rolling 4-deep B pipeline
        bf16x8 afr[2][4];   // A double-buffer (LDS latency ~120cyc)
        const u16* Wp = Wct + (w * 64 + m) * 192 + q8;
#pragma unroll
        for (int d = 0; d < 4; ++d)
#pragma unroll
            for (int nt = 0; nt < 4; ++nt)
                bfr[d][nt] = *(const bf16x8*)(Wp + nt * 16 * 192 + d * 32);
#pragma unroll
        for (int r = 0; r < 4; ++r)
            afr[0][r] = *(const bf16x8*)&buf[(r * 16 + m) * 264 + q8];
#pragma unroll
        for (int kc = 0; kc < 6; ++kc) {
            if (kc < 5) {
                int koff2 = (kc + 1) * 32 + q8;
#pragma unroll
                for (int r = 0; r < 4; ++r)
                    afr[(kc + 1) & 1][r] = *(const bf16x8*)&buf[(r * 16 + m) * 264 + koff2];
            }
#pragma unroll
            for (int nt = 0; nt < 4; ++nt) {
                acc[0][nt] = MFMA16(afr[kc & 1][0], bfr[kc & 3][nt], acc[0][nt]);
                acc[1][nt] = MFMA16(afr[kc & 1][1], bfr[kc & 3][nt], acc[1][nt]);
                acc[2][nt] = MFMA16(afr[kc & 1][2], bfr[kc & 3][nt], acc[2][nt]);
                acc[3][nt] = MFMA16(afr[kc & 1][3], bfr[kc & 3][nt], acc[3][nt]);
            }
            if (kc + 4 < 6) {
#pragma unroll
                for (int nt = 0; nt < 4; ++nt)
                    bfr[kc & 3][nt] = *(const bf16x8*)(Wp + nt * 16 * 192 + (kc + 4) * 32);
            }
        }
        __syncthreads();   // all waves done reading A0; safe to overwrite
#pragma unroll
        for (int mt = 0; mt < 4; ++mt)
#pragma unroll
            for (int nt = 0; nt < 4; ++nt) {
                int col = w * 64 + nt * 16 + m;
                float bcv = bc[col];
#pragma unroll
                for (int i = 0; i < 4; ++i) {
                    int row = mt * 16 + quad * 4 + i;
                    buf[row * 264 + col] = f2bf(swish_f(acc[mt][nt][i] + bcv, sp));
                }
            }
    }
    __syncthreads();

    // ---- GEMM2: h2 = A1[64x256] @ W1[256x256], +b1, swish (regs -> buf)
    {
        f32x4 acc[4][4] = {};
        bf16x8 bfr[4][4];
        bf16x8 afr[2][4];
        const u16* Wp = W1t + (w * 64 + m) * 256 + q8;
#pragma unroll
        for (int d = 0; d < 4; ++d)
#pragma unroll
            for (int nt = 0; nt < 4; ++nt)
                bfr[d][nt] = *(const bf16x8*)(Wp + nt * 16 * 256 + d * 32);
#pragma unroll
        for (int r = 0; r < 4; ++r)
            afr[0][r] = *(const bf16x8*)&buf[(r * 16 + m) * 264 + q8];
#pragma unroll
        for (int kc = 0; kc < 8; ++kc) {
            if (kc < 7) {
                int koff2 = (kc + 1) * 32 + q8;
#pragma unroll
                for (int r = 0; r < 4; ++r)
                    afr[(kc + 1) & 1][r] = *(const bf16x8*)&buf[(r * 16 + m) * 264 + koff2];
            }
#pragma unroll
            for (int nt = 0; nt < 4; ++nt) {
                acc[0][nt] = MFMA16(afr[kc & 1][0], bfr[kc & 3][nt], acc[0][nt]);
                acc[1][nt] = MFMA16(afr[kc & 1][1], bfr[kc & 3][nt], acc[1][nt]);
                acc[2][nt] = MFMA16(afr[kc & 1][2], bfr[kc & 3][nt], acc[2][nt]);
                acc[3][nt] = MFMA16(afr[kc & 1][3], bfr[kc & 3][nt], acc[3][nt]);
            }
            if (kc + 4 < 8) {
#pragma unroll
                for (int nt = 0; nt < 4; ++nt)
                    bfr[kc & 3][nt] = *(const bf16x8*)(Wp + nt * 16 * 256 + (kc + 4) * 32);
            }
        }
        __syncthreads();   // all waves done reading h; safe to overwrite
#pragma unroll
        for (int mt = 0; mt < 4; ++mt)
#pragma unroll
            for (int nt = 0; nt < 4; ++nt) {
                int col = w * 64 + nt * 16 + m;
                float b1v = b1[col];
#pragma unroll
                for (int i = 0; i < 4; ++i) {
                    int row = mt * 16 + quad * 4 + i;
                    buf[row * 264 + col] = f2bf(swish_f(acc[mt][nt][i] + b1v, sp));
                }
            }
    }
    __syncthreads();

    // ---- GEMM3: Fx = A2[64x256] @ W2[256x64], +b2; out = Fx + x, Fx
    {
        f32x4 acc3[4] = {};
        bf16x8 bfr[8];      // whole B panel preloaded (8 x 16B = 32 VGPR)
        bf16x8 afr[2][4];
        const u16* Wp = W2t + (w * 16 + m) * 256 + q8;
#pragma unroll
        for (int d = 0; d < 8; ++d) bfr[d] = *(const bf16x8*)(Wp + d * 32);
#pragma unroll
        for (int r = 0; r < 4; ++r)
            afr[0][r] = *(const bf16x8*)&buf[(r * 16 + m) * 264 + q8];
#pragma unroll
        for (int kc = 0; kc < 8; ++kc) {
            if (kc < 7) {
                int koff2 = (kc + 1) * 32 + q8;
#pragma unroll
                for (int r = 0; r < 4; ++r)
                    afr[(kc + 1) & 1][r] = *(const bf16x8*)&buf[(r * 16 + m) * 264 + koff2];
            }
            acc3[0] = MFMA16(afr[kc & 1][0], bfr[kc], acc3[0]);
            acc3[1] = MFMA16(afr[kc & 1][1], bfr[kc], acc3[1]);
            acc3[2] = MFMA16(afr[kc & 1][2], bfr[kc], acc3[2]);
            acc3[3] = MFMA16(afr[kc & 1][3], bfr[kc], acc3[3]);
        }
        int col = w * 16 + m;
        float b2v = b2[col];
#pragma unroll
        for (int mt = 0; mt < 4; ++mt)
#pragma unroll
            for (int i = 0; i < 4; ++i) {
                int row = mt * 16 + quad * 4 + i;
                size_t g = ((size_t)blockIdx.x * 64 + row) * 64 + col;
                float f = acc3[mt][i] + b2v;
                out[g] = f + x[g];
                out[OUT_OFF_ + g] = f;
            }
    }
}

extern "C" void kernel_launch(void* const* d_in, const int* in_sizes, int n_in,
                              void* d_out, int out_size, void* d_ws, size_t ws_size,
                              hipStream_t stream) {
    const float* x    = (const float*)d_in[0];
    const float* ew   = (const float*)d_in[1];
    const float* Wc   = (const float*)d_in[2];
    const float* bc   = (const float*)d_in[3];
    const float* W1   = (const float*)d_in[4];
    const float* b1   = (const float*)d_in[5];
    const float* W2   = (const float*)d_in[6];
    const float* b2   = (const float*)d_in[7];
    const float* beta = (const float*)d_in[8];
    const int*   ei   = (const int*)d_in[9];
    const int* src = ei;
    const int* dst = ei + E_;
    float* out = (float*)d_out;

    // workspace layout (float units)
    float* ws = (float*)d_ws;
    float* deg    = ws + 0;                 // N
    float* dis    = ws + 10000;             // N
    int*   cnt    = (int*)(ws + 20000);     // N
    int*   offs   = (int*)(ws + 30000);     // N+1 (pad to 10008)
    int*   cursor = (int*)(ws + 40008);     // N
    int*   ssrc   = (int*)(ws + 50008);     // E
    float* sw     = ws + 210008;            // E
    u16*   xbf    = (u16*)(ws + 370008);    // B*N*C u16
    u16*   Tx1    = (u16*)(ws + 2930008);   // B*N*C u16
    u16*   Tx2    = (u16*)(ws + 5490008);   // B*N*C u16
    u16*   Wct    = (u16*)(ws + 8050008);   // 49152 u16
    u16*   W1t    = (u16*)(ws + 8074584);   // 65536 u16
    u16*   W2t    = (u16*)(ws + 8107352);   // 16384 u16

    hipMemsetAsync(deg, 0, (size_t)N_ * sizeof(float), stream);
    hipMemsetAsync(cnt, 0, (size_t)N_ * sizeof(int), stream);

    k_deg<<<(E_ + 255) / 256, 256, 0, stream>>>(dst, ew, deg, cnt);
    k_dis<<<(N_ + 255) / 256, 256, 0, stream>>>(deg, dis);
    k_scan<<<1, 1024, 0, stream>>>(cnt, offs, cursor);
    k_scatter<<<(E_ + 255) / 256, 256, 0, stream>>>(src, dst, ew, dis, cursor, ssrc, sw);
    k_prepw<<<(131072 + (B_ * N_ * C_) / 4 + 255) / 256, 256, 0, stream>>>(
        Wc, W1, W2, x, Wct, W1t, W2t, xbf);
    k_prop<<<N_ / 4 * 8, 256, 0, stream>>>(xbf, offs, ssrc, sw, xbf, Tx1, 0);
    k_prop<<<N_ / 4 * 8, 256, 0, stream>>>(Tx1, offs, ssrc, sw, xbf, Tx2, 1);
    k_fused<<<ROWS_ / 64, 256, 0, stream>>>(x, xbf, Tx1, Tx2, Wct, bc, W1t, b1,
                                            W2t, b2, beta, out);
}

// Round 4
// 271.326 us; speedup vs baseline: 1.0292x; 1.0292x over previous
//
#include <hip/hip_runtime.h>
#include <cstdint>
#include <cstddef>

#define B_ 8
#define N_ 10000
#define C_ 64
#define DIM_ 256
#define E_ 160000
#define ROWS_ (B_ * N_)            // 80000
#define OUT_OFF_ ((size_t)B_ * N_ * C_)  // 5,120,000

typedef unsigned short u16;
typedef unsigned int u32;
typedef __attribute__((ext_vector_type(8))) short bf16x8;
typedef __attribute__((ext_vector_type(4))) float f32x4;

__device__ __forceinline__ u16 f2bf(float f) {
    unsigned int u = __float_as_uint(f);
    unsigned int r = u + 0x7FFF + ((u >> 16) & 1);  // RNE
    return (u16)(r >> 16);
}
__device__ __forceinline__ float bf2f(u32 h) {      // low 16 bits hold bf16
    return __uint_as_float(h << 16);
}
__device__ __forceinline__ unsigned int pack2(float a, float b) {
    return (unsigned int)f2bf(a) | ((unsigned int)f2bf(b) << 16);
}
__device__ __forceinline__ float swish_f(float v, float sp) {
    float e = __expf(-v * sp);
    float s = __builtin_amdgcn_rcpf(1.0f + e);
    return v * s * (1.0f / 1.1f);
}

#define MFMA16(a, b, c) __builtin_amdgcn_mfma_f32_16x16x32_bf16(a, b, c, 0, 0, 0)

// ---- graph preprocessing -------------------------------------------------

__global__ void k_deg(const int* __restrict__ dst, const float* __restrict__ ew,
                      float* __restrict__ deg, int* __restrict__ cnt) {
    int e = blockIdx.x * 256 + threadIdx.x;
    if (e < E_) {
        int d = dst[e];
        atomicAdd(&deg[d], ew[e]);
        atomicAdd(&cnt[d], 1);
    }
}

__global__ void k_dis(const float* __restrict__ deg, float* __restrict__ dis) {
    int n = blockIdx.x * 256 + threadIdx.x;
    if (n < N_) {
        float d = deg[n];
        dis[n] = d > 0.f ? rsqrtf(d) : 0.f;
    }
}

__global__ void k_scan(const int* __restrict__ cnt, int* __restrict__ offs,
                       int* __restrict__ cursor) {
    __shared__ int part[1024];
    int t = threadIdx.x;
    const int CH = 10;
    int base = t * CH;
    int s = 0;
    for (int i = 0; i < CH; i++) {
        int idx = base + i;
        if (idx < N_) s += cnt[idx];
    }
    part[t] = s;
    __syncthreads();
    for (int off = 1; off < 1024; off <<= 1) {
        int v = 0;
        if (t >= off) v = part[t - off];
        __syncthreads();
        if (t >= off) part[t] += v;
        __syncthreads();
    }
    int run = (t > 0) ? part[t - 1] : 0;
    for (int i = 0; i < CH; i++) {
        int idx = base + i;
        if (idx < N_) {
            offs[idx] = run;
            cursor[idx] = run;
            run += cnt[idx];
        }
    }
    if (t == 1023) offs[N_] = run;
}

__global__ void k_scatter(const int* __restrict__ src, const int* __restrict__ dst,
                          const float* __restrict__ ew, const float* __restrict__ dis,
                          int* __restrict__ cursor, int* __restrict__ ssrc,
                          float* __restrict__ sw) {
    int e = blockIdx.x * 256 + threadIdx.x;
    if (e < E_) {
        int sn = src[e], dn = dst[e];
        float w = -(dis[sn] * ew[e] * dis[dn]);
        int p = atomicAdd(&cursor[dn], 1);
        ssrc[p] = sn;
        sw[p] = w;
    }
}

// weight transpose to N-major bf16 + vectorized x cast
__global__ void k_prepw(const float* __restrict__ Wc, const float* __restrict__ W1,
                        const float* __restrict__ W2, const float* __restrict__ x,
                        u16* __restrict__ Wct, u16* __restrict__ W1t,
                        u16* __restrict__ W2t, u16* __restrict__ xbf) {
    int i = blockIdx.x * 256 + threadIdx.x;
    if (i < 49152) {
        int nr = i / 192, k = i % 192;
        Wct[i] = f2bf(Wc[k * 256 + nr]);
    } else if (i < 114688) {
        int j = i - 49152;
        int nr = j >> 8, k = j & 255;
        W1t[j] = f2bf(W1[k * 256 + nr]);
    } else if (i < 131072) {
        int j = i - 114688;
        int nr = j >> 8, k = j & 255;
        W2t[j] = f2bf(W2[k * 64 + nr]);
    } else {
        int j = i - 131072;
        if (j < (B_ * N_ * C_) / 4) {
            float4 v = ((const float4*)x)[j];
            uint2 pv = {pack2(v.x, v.y), pack2(v.z, v.w)};
            ((uint2*)xbf)[j] = pv;
        }
    }
}

// bf16 gather SpMM. One wave per (batch, node); XCD-batch swizzle (b = blk&7).
// mode==1: O = 2*sum - xin  (fused Tx2 computation)
__global__ __launch_bounds__(256) void k_prop(
        const u16* __restrict__ T, const int* __restrict__ offs,
        const int* __restrict__ ssrc, const float* __restrict__ sw,
        const u16* __restrict__ xin, u16* __restrict__ O, int mode) {
    int w = __builtin_amdgcn_readfirstlane(threadIdx.x >> 6);
    int lane = threadIdx.x & 63;
    int b = blockIdx.x & 7;
    int nb = blockIdx.x >> 3;
    int n = nb * 4 + w;
    const u16* Tb = T + (size_t)b * (N_ * C_);
    int s = offs[n], e = offs[n + 1];
    float sum = 0.f;
    int j = s;
    for (; j < e && (j & 3); ++j) sum += bf2f(Tb[(size_t)ssrc[j] * 64 + lane]) * sw[j];
    for (; j + 4 <= e; j += 4) {
        int4 idx = *(const int4*)&ssrc[j];
        float4 wv = *(const float4*)&sw[j];
        sum += bf2f(Tb[(size_t)idx.x * 64 + lane]) * wv.x
             + bf2f(Tb[(size_t)idx.y * 64 + lane]) * wv.y
             + bf2f(Tb[(size_t)idx.z * 64 + lane]) * wv.z
             + bf2f(Tb[(size_t)idx.w * 64 + lane]) * wv.w;
    }
    for (; j < e; ++j) sum += bf2f(Tb[(size_t)ssrc[j] * 64 + lane]) * sw[j];
    size_t g = ((size_t)b * N_ + n) * 64 + lane;
    float v = sum;
    if (mode == 1) v = 2.f * sum - bf2f(xin[g]);
    O[g] = f2bf(v);
}

// ---- fused cheb-einsum + MLP, bf16 MFMA, M=64 rows/block -----------------
// 256 threads (4 waves); wave w owns a 64-col slice (16-col for GEMM3).
// R4: single 33.8 KB LDS buffer reused A0 -> h -> h2 (R3) BUT launch bound
// restored to (256,2). R3's (256,4) clamped the allocator to the 64-VGPR tier
// and spilled (+50 MB scratch HBM traffic, 66->81 µs). The natural 88-VGPR
// allocation already sits in the <=128 tier, which the HW schedules at
// 4 waves/EU = 4 blocks/CU given 33.8 KB LDS — occupancy without spills.
__global__ __launch_bounds__(256, 2) void k_fused(
        const float* __restrict__ x, const u16* __restrict__ xbf,
        const u16* __restrict__ Tx1, const u16* __restrict__ Tx2,
        const u16* __restrict__ Wct, const float* __restrict__ bc,
        const u16* __restrict__ W1t, const float* __restrict__ b1,
        const u16* __restrict__ W2t, const float* __restrict__ b2,
        const float* __restrict__ beta, float* __restrict__ out) {
    __shared__ u16 buf[64 * 264];   // A0 (cols 0..191) -> h (0..255) -> h2
    int t = threadIdx.x;

    // stage A0 = [xbf | Tx1 | Tx2] bf16, row-major, K-stride 264
    {
        size_t base = (size_t)blockIdx.x * 1024;  // uint2 units (64 rows x 16)
        const uint2* xb = (const uint2*)xbf + base;
        const uint2* tb = (const uint2*)Tx1 + base;
        const uint2* pb = (const uint2*)Tx2 + base;
#pragma unroll
        for (int rep = 0; rep < 4; ++rep) {
            int p = t + rep * 256;
            int r = p >> 4, c4 = p & 15;
            *(uint2*)&buf[r * 264 + c4 * 4] = xb[p];
            *(uint2*)&buf[r * 264 + 64 + c4 * 4] = tb[p];
            *(uint2*)&buf[r * 264 + 128 + c4 * 4] = pb[p];
        }
    }
    __syncthreads();

    float sp = logf(1.f + expf(beta[0]));
    int lane = t & 63, w = t >> 6;
    int m = lane & 15, quad = lane >> 4;
    int q8 = quad * 8;

    // ---- GEMM1: h = A0[64x192] @ Wc[192x256], +bc, swish (regs -> buf)
    {
        f32x4 acc[4][4] = {};
        bf16x8 bfr[4][4];   // rolling 4-deep B pipeline
        bf16x8 afr[2][4];   // A double-buffer (LDS latency ~120cyc)
        const u16* Wp = Wct + (w * 64 + m) * 192 + q8;
#pragma unroll
        for (int d = 0; d < 4; ++d)
#pragma unroll
            for (int nt = 0; nt < 4; ++nt)
                bfr[d][nt] = *(const bf16x8*)(Wp + nt * 16 * 192 + d * 32);
#pragma unroll
        for (int r = 0; r < 4; ++r)
            afr[0][r] = *(const bf16x8*)&buf[(r * 16 + m) * 264 + q8];
#pragma unroll
        for (int kc = 0; kc < 6; ++kc) {
            if (kc < 5) {
                int koff2 = (kc + 1) * 32 + q8;
#pragma unroll
                for (int r = 0; r < 4; ++r)
                    afr[(kc + 1) & 1][r] = *(const bf16x8*)&buf[(r * 16 + m) * 264 + koff2];
            }
#pragma unroll
            for (int nt = 0; nt < 4; ++nt) {
                acc[0][nt] = MFMA16(afr[kc & 1][0], bfr[kc & 3][nt], acc[0][nt]);
                acc[1][nt] = MFMA16(afr[kc & 1][1], bfr[kc & 3][nt], acc[1][nt]);
                acc[2][nt] = MFMA16(afr[kc & 1][2], bfr[kc & 3][nt], acc[2][nt]);
                acc[3][nt] = MFMA16(afr[kc & 1][3], bfr[kc & 3][nt], acc[3][nt]);
            }
            if (kc + 4 < 6) {
#pragma unroll
                for (int nt = 0; nt < 4; ++nt)
                    bfr[kc & 3][nt] = *(const bf16x8*)(Wp + nt * 16 * 192 + (kc + 4) * 32);
            }
        }
        __syncthreads();   // all waves done reading A0; safe to overwrite
#pragma unroll
        for (int mt = 0; mt < 4; ++mt)
#pragma unroll
            for (int nt = 0; nt < 4; ++nt) {
                int col = w * 64 + nt * 16 + m;
                float bcv = bc[col];
#pragma unroll
                for (int i = 0; i < 4; ++i) {
                    int row = mt * 16 + quad * 4 + i;
                    buf[row * 264 + col] = f2bf(swish_f(acc[mt][nt][i] + bcv, sp));
                }
            }
    }
    __syncthreads();

    // ---- GEMM2: h2 = A1[64x256] @ W1[256x256], +b1, swish (regs -> buf)
    {
        f32x4 acc[4][4] = {};
        bf16x8 bfr[4][4];
        bf16x8 afr[2][4];
        const u16* Wp = W1t + (w * 64 + m) * 256 + q8;
#pragma unroll
        for (int d = 0; d < 4; ++d)
#pragma unroll
            for (int nt = 0; nt < 4; ++nt)
                bfr[d][nt] = *(const bf16x8*)(Wp + nt * 16 * 256 + d * 32);
#pragma unroll
        for (int r = 0; r < 4; ++r)
            afr[0][r] = *(const bf16x8*)&buf[(r * 16 + m) * 264 + q8];
#pragma unroll
        for (int kc = 0; kc < 8; ++kc) {
            if (kc < 7) {
                int koff2 = (kc + 1) * 32 + q8;
#pragma unroll
                for (int r = 0; r < 4; ++r)
                    afr[(kc + 1) & 1][r] = *(const bf16x8*)&buf[(r * 16 + m) * 264 + koff2];
            }
#pragma unroll
            for (int nt = 0; nt < 4; ++nt) {
                acc[0][nt] = MFMA16(afr[kc & 1][0], bfr[kc & 3][nt], acc[0][nt]);
                acc[1][nt] = MFMA16(afr[kc & 1][1], bfr[kc & 3][nt], acc[1][nt]);
                acc[2][nt] = MFMA16(afr[kc & 1][2], bfr[kc & 3][nt], acc[2][nt]);
                acc[3][nt] = MFMA16(afr[kc & 1][3], bfr[kc & 3][nt], acc[3][nt]);
            }
            if (kc + 4 < 8) {
#pragma unroll
                for (int nt = 0; nt < 4; ++nt)
                    bfr[kc & 3][nt] = *(const bf16x8*)(Wp + nt * 16 * 256 + (kc + 4) * 32);
            }
        }
        __syncthreads();   // all waves done reading h; safe to overwrite
#pragma unroll
        for (int mt = 0; mt < 4; ++mt)
#pragma unroll
            for (int nt = 0; nt < 4; ++nt) {
                int col = w * 64 + nt * 16 + m;
                float b1v = b1[col];
#pragma unroll
                for (int i = 0; i < 4; ++i) {
                    int row = mt * 16 + quad * 4 + i;
                    buf[row * 264 + col] = f2bf(swish_f(acc[mt][nt][i] + b1v, sp));
                }
            }
    }
    __syncthreads();

    // ---- GEMM3: Fx = A2[64x256] @ W2[256x64], +b2; out = Fx + x, Fx
    {
        f32x4 acc3[4] = {};
        bf16x8 bfr[8];      // whole B panel preloaded (8 x 16B = 32 VGPR)
        bf16x8 afr[2][4];
        const u16* Wp = W2t + (w * 16 + m) * 256 + q8;
#pragma unroll
        for (int d = 0; d < 8; ++d) bfr[d] = *(const bf16x8*)(Wp + d * 32);
#pragma unroll
        for (int r = 0; r < 4; ++r)
            afr[0][r] = *(const bf16x8*)&buf[(r * 16 + m) * 264 + q8];
#pragma unroll
        for (int kc = 0; kc < 8; ++kc) {
            if (kc < 7) {
                int koff2 = (kc + 1) * 32 + q8;
#pragma unroll
                for (int r = 0; r < 4; ++r)
                    afr[(kc + 1) & 1][r] = *(const bf16x8*)&buf[(r * 16 + m) * 264 + koff2];
            }
            acc3[0] = MFMA16(afr[kc & 1][0], bfr[kc], acc3[0]);
            acc3[1] = MFMA16(afr[kc & 1][1], bfr[kc], acc3[1]);
            acc3[2] = MFMA16(afr[kc & 1][2], bfr[kc], acc3[2]);
            acc3[3] = MFMA16(afr[kc & 1][3], bfr[kc], acc3[3]);
        }
        int col = w * 16 + m;
        float b2v = b2[col];
#pragma unroll
        for (int mt = 0; mt < 4; ++mt)
#pragma unroll
            for (int i = 0; i < 4; ++i) {
                int row = mt * 16 + quad * 4 + i;
                size_t g = ((size_t)blockIdx.x * 64 + row) * 64 + col;
                float f = acc3[mt][i] + b2v;
                out[g] = f + x[g];
                out[OUT_OFF_ + g] = f;
            }
    }
}

extern "C" void kernel_launch(void* const* d_in, const int* in_sizes, int n_in,
                              void* d_out, int out_size, void* d_ws, size_t ws_size,
                              hipStream_t stream) {
    const float* x    = (const float*)d_in[0];
    const float* ew   = (const float*)d_in[1];
    const float* Wc   = (const float*)d_in[2];
    const float* bc   = (const float*)d_in[3];
    const float* W1   = (const float*)d_in[4];
    const float* b1   = (const float*)d_in[5];
    const float* W2   = (const float*)d_in[6];
    const float* b2   = (const float*)d_in[7];
    const float* beta = (const float*)d_in[8];
    const int*   ei   = (const int*)d_in[9];
    const int* src = ei;
    const int* dst = ei + E_;
    float* out = (float*)d_out;

    // workspace layout (float units)
    float* ws = (float*)d_ws;
    float* deg    = ws + 0;                 // N
    float* dis    = ws + 10000;             // N
    int*   cnt    = (int*)(ws + 20000);     // N
    int*   offs   = (int*)(ws + 30000);     // N+1 (pad to 10008)
    int*   cursor = (int*)(ws + 40008);     // N
    int*   ssrc   = (int*)(ws + 50008);     // E
    float* sw     = ws + 210008;            // E
    u16*   xbf    = (u16*)(ws + 370008);    // B*N*C u16
    u16*   Tx1    = (u16*)(ws + 2930008);   // B*N*C u16
    u16*   Tx2    = (u16*)(ws + 5490008);   // B*N*C u16
    u16*   Wct    = (u16*)(ws + 8050008);   // 49152 u16
    u16*   W1t    = (u16*)(ws + 8074584);   // 65536 u16
    u16*   W2t    = (u16*)(ws + 8107352);   // 16384 u16

    hipMemsetAsync(deg, 0, (size_t)N_ * sizeof(float), stream);
    hipMemsetAsync(cnt, 0, (size_t)N_ * sizeof(int), stream);

    k_deg<<<(E_ + 255) / 256, 256, 0, stream>>>(dst, ew, deg, cnt);
    k_dis<<<(N_ + 255) / 256, 256, 0, stream>>>(deg, dis);
    k_scan<<<1, 1024, 0, stream>>>(cnt, offs, cursor);
    k_scatter<<<(E_ + 255) / 256, 256, 0, stream>>>(src, dst, ew, dis, cursor, ssrc, sw);
    k_prepw<<<(131072 + (B_ * N_ * C_) / 4 + 255) / 256, 256, 0, stream>>>(
        Wc, W1, W2, x, Wct, W1t, W2t, xbf);
    k_prop<<<N_ / 4 * 8, 256, 0, stream>>>(xbf, offs, ssrc, sw, xbf, Tx1, 0);
    k_prop<<<N_ / 4 * 8, 256, 0, stream>>>(Tx1, offs, ssrc, sw, xbf, Tx2, 1);
    k_fused<<<ROWS_ / 64, 256, 0, stream>>>(x, xbf, Tx1, Tx2, Wct, bc, W1t, b1,
                                            W2t, b2, beta, out);
}

// Round 5
// 265.432 us; speedup vs baseline: 1.0520x; 1.0222x over previous
//
#include <hip/hip_runtime.h>
#include <cstdint>
#include <cstddef>

#define B_ 8
#define N_ 10000
#define C_ 64
#define DIM_ 256
#define E_ 160000
#define ROWS_ (B_ * N_)            // 80000
#define OUT_OFF_ ((size_t)B_ * N_ * C_)  // 5,120,000

typedef unsigned short u16;
typedef unsigned int u32;
typedef __attribute__((ext_vector_type(8))) short bf16x8;
typedef __attribute__((ext_vector_type(4))) float f32x4;

__device__ __forceinline__ u16 f2bf(float f) {
    unsigned int u = __float_as_uint(f);
    unsigned int r = u + 0x7FFF + ((u >> 16) & 1);  // RNE
    return (u16)(r >> 16);
}
__device__ __forceinline__ float bf2f(u32 h) {      // low 16 bits hold bf16
    return __uint_as_float(h << 16);
}
__device__ __forceinline__ unsigned int pack2(float a, float b) {
    return (unsigned int)f2bf(a) | ((unsigned int)f2bf(b) << 16);
}
__device__ __forceinline__ float swish_f(float v, float sp) {
    float e = __expf(-v * sp);
    float s = __builtin_amdgcn_rcpf(1.0f + e);
    return v * s * (1.0f / 1.1f);
}

#define MFMA16(a, b, c) __builtin_amdgcn_mfma_f32_16x16x32_bf16(a, b, c, 0, 0, 0)

// ---- graph preprocessing -------------------------------------------------

__global__ void k_deg(const int* __restrict__ dst, const float* __restrict__ ew,
                      float* __restrict__ deg, int* __restrict__ cnt) {
    int e = blockIdx.x * 256 + threadIdx.x;
    if (e < E_) {
        int d = dst[e];
        atomicAdd(&deg[d], ew[e]);
        atomicAdd(&cnt[d], 1);
    }
}

__global__ void k_dis(const float* __restrict__ deg, float* __restrict__ dis) {
    int n = blockIdx.x * 256 + threadIdx.x;
    if (n < N_) {
        float d = deg[n];
        dis[n] = d > 0.f ? rsqrtf(d) : 0.f;
    }
}

__global__ void k_scan(const int* __restrict__ cnt, int* __restrict__ offs,
                       int* __restrict__ cursor) {
    __shared__ int part[1024];
    int t = threadIdx.x;
    const int CH = 10;
    int base = t * CH;
    int s = 0;
    for (int i = 0; i < CH; i++) {
        int idx = base + i;
        if (idx < N_) s += cnt[idx];
    }
    part[t] = s;
    __syncthreads();
    for (int off = 1; off < 1024; off <<= 1) {
        int v = 0;
        if (t >= off) v = part[t - off];
        __syncthreads();
        if (t >= off) part[t] += v;
        __syncthreads();
    }
    int run = (t > 0) ? part[t - 1] : 0;
    for (int i = 0; i < CH; i++) {
        int idx = base + i;
        if (idx < N_) {
            offs[idx] = run;
            cursor[idx] = run;
            run += cnt[idx];
        }
    }
    if (t == 1023) offs[N_] = run;
}

__global__ void k_scatter(const int* __restrict__ src, const int* __restrict__ dst,
                          const float* __restrict__ ew, const float* __restrict__ dis,
                          int* __restrict__ cursor, int* __restrict__ ssrc,
                          float* __restrict__ sw) {
    int e = blockIdx.x * 256 + threadIdx.x;
    if (e < E_) {
        int sn = src[e], dn = dst[e];
        float w = -(dis[sn] * ew[e] * dis[dn]);
        int p = atomicAdd(&cursor[dn], 1);
        ssrc[p] = sn;
        sw[p] = w;
    }
}

// weight transpose to N-major bf16 + vectorized x cast
__global__ void k_prepw(const float* __restrict__ Wc, const float* __restrict__ W1,
                        const float* __restrict__ W2, const float* __restrict__ x,
                        u16* __restrict__ Wct, u16* __restrict__ W1t,
                        u16* __restrict__ W2t, u16* __restrict__ xbf) {
    int i = blockIdx.x * 256 + threadIdx.x;
    if (i < 49152) {
        int nr = i / 192, k = i % 192;
        Wct[i] = f2bf(Wc[k * 256 + nr]);
    } else if (i < 114688) {
        int j = i - 49152;
        int nr = j >> 8, k = j & 255;
        W1t[j] = f2bf(W1[k * 256 + nr]);
    } else if (i < 131072) {
        int j = i - 114688;
        int nr = j >> 8, k = j & 255;
        W2t[j] = f2bf(W2[k * 64 + nr]);
    } else {
        int j = i - 131072;
        if (j < (B_ * N_ * C_) / 4) {
            float4 v = ((const float4*)x)[j];
            uint2 pv = {pack2(v.x, v.y), pack2(v.z, v.w)};
            ((uint2*)xbf)[j] = pv;
        }
    }
}

// bf16 gather SpMM. One wave per (batch, node); XCD-batch swizzle (b = blk&7).
// mode==1: O = 2*sum - xin  (fused Tx2 computation)
__global__ __launch_bounds__(256) void k_prop(
        const u16* __restrict__ T, const int* __restrict__ offs,
        const int* __restrict__ ssrc, const float* __restrict__ sw,
        const u16* __restrict__ xin, u16* __restrict__ O, int mode) {
    int w = __builtin_amdgcn_readfirstlane(threadIdx.x >> 6);
    int lane = threadIdx.x & 63;
    int b = blockIdx.x & 7;
    int nb = blockIdx.x >> 3;
    int n = nb * 4 + w;
    const u16* Tb = T + (size_t)b * (N_ * C_);
    int s = offs[n], e = offs[n + 1];
    float sum = 0.f;
    int j = s;
    for (; j < e && (j & 3); ++j) sum += bf2f(Tb[(size_t)ssrc[j] * 64 + lane]) * sw[j];
    for (; j + 4 <= e; j += 4) {
        int4 idx = *(const int4*)&ssrc[j];
        float4 wv = *(const float4*)&sw[j];
        sum += bf2f(Tb[(size_t)idx.x * 64 + lane]) * wv.x
             + bf2f(Tb[(size_t)idx.y * 64 + lane]) * wv.y
             + bf2f(Tb[(size_t)idx.z * 64 + lane]) * wv.z
             + bf2f(Tb[(size_t)idx.w * 64 + lane]) * wv.w;
    }
    for (; j < e; ++j) sum += bf2f(Tb[(size_t)ssrc[j] * 64 + lane]) * sw[j];
    size_t g = ((size_t)b * N_ + n) * 64 + lane;
    float v = sum;
    if (mode == 1) v = 2.f * sum - bf2f(xin[g]);
    O[g] = f2bf(v);
}

// ---- fused cheb-einsum + MLP, bf16 MFMA, M=64 rows/block -----------------
// 256 threads (4 waves); wave w owns a 64-col slice (16-col for GEMM3).
// R5: single 33.8 KB LDS buffer (A0 -> h -> h2) + NO waves-per-EU clamp.
// Residency ladder evidence: (256,2) pinned HW at 2 blocks/CU (R4 occ 18.3
// with LDS allowing 4); (256,4) clamped VGPR to 64 and spilled (R3). Single-
// arg bounds (R0 style) let the allocator settle ~88-115 VGPR (<=128 tier)
// and the HW pack 4 blocks/CU by LDS — 4 independent desynced streams.
__global__ __launch_bounds__(256) void k_fused(
        const float* __restrict__ x, const u16* __restrict__ xbf,
        const u16* __restrict__ Tx1, const u16* __restrict__ Tx2,
        const u16* __restrict__ Wct, const float* __restrict__ bc,
        const u16* __restrict__ W1t, const float* __restrict__ b1,
        const u16* __restrict__ W2t, const float* __restrict__ b2,
        const float* __restrict__ beta, float* __restrict__ out) {
    __shared__ u16 buf[64 * 264];   // A0 (cols 0..191) -> h (0..255) -> h2
    int t = threadIdx.x;

    // stage A0 = [xbf | Tx1 | Tx2] bf16, row-major, K-stride 264
    {
        size_t base = (size_t)blockIdx.x * 1024;  // uint2 units (64 rows x 16)
        const uint2* xb = (const uint2*)xbf + base;
        const uint2* tb = (const uint2*)Tx1 + base;
        const uint2* pb = (const uint2*)Tx2 + base;
#pragma unroll
        for (int rep = 0; rep < 4; ++rep) {
            int p = t + rep * 256;
            int r = p >> 4, c4 = p & 15;
            *(uint2*)&buf[r * 264 + c4 * 4] = xb[p];
            *(uint2*)&buf[r * 264 + 64 + c4 * 4] = tb[p];
            *(uint2*)&buf[r * 264 + 128 + c4 * 4] = pb[p];
        }
    }
    __syncthreads();

    float sp = logf(1.f + expf(beta[0]));
    int lane = t & 63, w = t >> 6;
    int m = lane & 15, quad = lane >> 4;
    int q8 = quad * 8;

    // ---- GEMM1: h = A0[64x192] @ Wc[192x256], +bc, swish (regs -> buf)
    {
        f32x4 acc[4][4] = {};
        bf16x8 bfr[4][4];   // rolling 4-deep B pipeline
        bf16x8 afr[2][4];   // A double-buffer (LDS latency ~120cyc)
        const u16* Wp = Wct + (w * 64 + m) * 192 + q8;
#pragma unroll
        for (int d = 0; d < 4; ++d)
#pragma unroll
            for (int nt = 0; nt < 4; ++nt)
                bfr[d][nt] = *(const bf16x8*)(Wp + nt * 16 * 192 + d * 32);
#pragma unroll
        for (int r = 0; r < 4; ++r)
            afr[0][r] = *(const bf16x8*)&buf[(r * 16 + m) * 264 + q8];
#pragma unroll
        for (int kc = 0; kc < 6; ++kc) {
            if (kc < 5) {
                int koff2 = (kc + 1) * 32 + q8;
#pragma unroll
                for (int r = 0; r < 4; ++r)
                    afr[(kc + 1) & 1][r] = *(const bf16x8*)&buf[(r * 16 + m) * 264 + koff2];
            }
#pragma unroll
            for (int nt = 0; nt < 4; ++nt) {
                acc[0][nt] = MFMA16(afr[kc & 1][0], bfr[kc & 3][nt], acc[0][nt]);
                acc[1][nt] = MFMA16(afr[kc & 1][1], bfr[kc & 3][nt], acc[1][nt]);
                acc[2][nt] = MFMA16(afr[kc & 1][2], bfr[kc & 3][nt], acc[2][nt]);
                acc[3][nt] = MFMA16(afr[kc & 1][3], bfr[kc & 3][nt], acc[3][nt]);
            }
            if (kc + 4 < 6) {
#pragma unroll
                for (int nt = 0; nt < 4; ++nt)
                    bfr[kc & 3][nt] = *(const bf16x8*)(Wp + nt * 16 * 192 + (kc + 4) * 32);
            }
        }
        __syncthreads();   // all waves done reading A0; safe to overwrite
#pragma unroll
        for (int mt = 0; mt < 4; ++mt)
#pragma unroll
            for (int nt = 0; nt < 4; ++nt) {
                int col = w * 64 + nt * 16 + m;
                float bcv = bc[col];
#pragma unroll
                for (int i = 0; i < 4; ++i) {
                    int row = mt * 16 + quad * 4 + i;
                    buf[row * 264 + col] = f2bf(swish_f(acc[mt][nt][i] + bcv, sp));
                }
            }
    }
    __syncthreads();

    // ---- GEMM2: h2 = A1[64x256] @ W1[256x256], +b1, swish (regs -> buf)
    {
        f32x4 acc[4][4] = {};
        bf16x8 bfr[4][4];
        bf16x8 afr[2][4];
        const u16* Wp = W1t + (w * 64 + m) * 256 + q8;
#pragma unroll
        for (int d = 0; d < 4; ++d)
#pragma unroll
            for (int nt = 0; nt < 4; ++nt)
                bfr[d][nt] = *(const bf16x8*)(Wp + nt * 16 * 256 + d * 32);
#pragma unroll
        for (int r = 0; r < 4; ++r)
            afr[0][r] = *(const bf16x8*)&buf[(r * 16 + m) * 264 + q8];
#pragma unroll
        for (int kc = 0; kc < 8; ++kc) {
            if (kc < 7) {
                int koff2 = (kc + 1) * 32 + q8;
#pragma unroll
                for (int r = 0; r < 4; ++r)
                    afr[(kc + 1) & 1][r] = *(const bf16x8*)&buf[(r * 16 + m) * 264 + koff2];
            }
#pragma unroll
            for (int nt = 0; nt < 4; ++nt) {
                acc[0][nt] = MFMA16(afr[kc & 1][0], bfr[kc & 3][nt], acc[0][nt]);
                acc[1][nt] = MFMA16(afr[kc & 1][1], bfr[kc & 3][nt], acc[1][nt]);
                acc[2][nt] = MFMA16(afr[kc & 1][2], bfr[kc & 3][nt], acc[2][nt]);
                acc[3][nt] = MFMA16(afr[kc & 1][3], bfr[kc & 3][nt], acc[3][nt]);
            }
            if (kc + 4 < 8) {
#pragma unroll
                for (int nt = 0; nt < 4; ++nt)
                    bfr[kc & 3][nt] = *(const bf16x8*)(Wp + nt * 16 * 256 + (kc + 4) * 32);
            }
        }
        __syncthreads();   // all waves done reading h; safe to overwrite
#pragma unroll
        for (int mt = 0; mt < 4; ++mt)
#pragma unroll
            for (int nt = 0; nt < 4; ++nt) {
                int col = w * 64 + nt * 16 + m;
                float b1v = b1[col];
#pragma unroll
                for (int i = 0; i < 4; ++i) {
                    int row = mt * 16 + quad * 4 + i;
                    buf[row * 264 + col] = f2bf(swish_f(acc[mt][nt][i] + b1v, sp));
                }
            }
    }
    __syncthreads();

    // ---- GEMM3: Fx = A2[64x256] @ W2[256x64], +b2; out = Fx + x, Fx
    {
        f32x4 acc3[4] = {};
        bf16x8 bfr[8];      // whole B panel preloaded (8 x 16B = 32 VGPR)
        bf16x8 afr[2][4];
        const u16* Wp = W2t + (w * 16 + m) * 256 + q8;
#pragma unroll
        for (int d = 0; d < 8; ++d) bfr[d] = *(const bf16x8*)(Wp + d * 32);
#pragma unroll
        for (int r = 0; r < 4; ++r)
            afr[0][r] = *(const bf16x8*)&buf[(r * 16 + m) * 264 + q8];
#pragma unroll
        for (int kc = 0; kc < 8; ++kc) {
            if (kc < 7) {
                int koff2 = (kc + 1) * 32 + q8;
#pragma unroll
                for (int r = 0; r < 4; ++r)
                    afr[(kc + 1) & 1][r] = *(const bf16x8*)&buf[(r * 16 + m) * 264 + koff2];
            }
            acc3[0] = MFMA16(afr[kc & 1][0], bfr[kc], acc3[0]);
            acc3[1] = MFMA16(afr[kc & 1][1], bfr[kc], acc3[1]);
            acc3[2] = MFMA16(afr[kc & 1][2], bfr[kc], acc3[2]);
            acc3[3] = MFMA16(afr[kc & 1][3], bfr[kc], acc3[3]);
        }
        int col = w * 16 + m;
        float b2v = b2[col];
#pragma unroll
        for (int mt = 0; mt < 4; ++mt)
#pragma unroll
            for (int i = 0; i < 4; ++i) {
                int row = mt * 16 + quad * 4 + i;
                size_t g = ((size_t)blockIdx.x * 64 + row) * 64 + col;
                float f = acc3[mt][i] + b2v;
                out[g] = f + x[g];
                out[OUT_OFF_ + g] = f;
            }
    }
}

extern "C" void kernel_launch(void* const* d_in, const int* in_sizes, int n_in,
                              void* d_out, int out_size, void* d_ws, size_t ws_size,
                              hipStream_t stream) {
    const float* x    = (const float*)d_in[0];
    const float* ew   = (const float*)d_in[1];
    const float* Wc   = (const float*)d_in[2];
    const float* bc   = (const float*)d_in[3];
    const float* W1   = (const float*)d_in[4];
    const float* b1   = (const float*)d_in[5];
    const float* W2   = (const float*)d_in[6];
    const float* b2   = (const float*)d_in[7];
    const float* beta = (const float*)d_in[8];
    const int*   ei   = (const int*)d_in[9];
    const int* src = ei;
    const int* dst = ei + E_;
    float* out = (float*)d_out;

    // workspace layout (float units)
    float* ws = (float*)d_ws;
    float* deg    = ws + 0;                 // N
    float* dis    = ws + 10000;             // N
    int*   cnt    = (int*)(ws + 20000);     // N
    int*   offs   = (int*)(ws + 30000);     // N+1 (pad to 10008)
    int*   cursor = (int*)(ws + 40008);     // N
    int*   ssrc   = (int*)(ws + 50008);     // E
    float* sw     = ws + 210008;            // E
    u16*   xbf    = (u16*)(ws + 370008);    // B*N*C u16
    u16*   Tx1    = (u16*)(ws + 2930008);   // B*N*C u16
    u16*   Tx2    = (u16*)(ws + 5490008);   // B*N*C u16
    u16*   Wct    = (u16*)(ws + 8050008);   // 49152 u16
    u16*   W1t    = (u16*)(ws + 8074584);   // 65536 u16
    u16*   W2t    = (u16*)(ws + 8107352);   // 16384 u16

    hipMemsetAsync(deg, 0, (size_t)N_ * sizeof(float), stream);
    hipMemsetAsync(cnt, 0, (size_t)N_ * sizeof(int), stream);

    k_deg<<<(E_ + 255) / 256, 256, 0, stream>>>(dst, ew, deg, cnt);
    k_dis<<<(N_ + 255) / 256, 256, 0, stream>>>(deg, dis);
    k_scan<<<1, 1024, 0, stream>>>(cnt, offs, cursor);
    k_scatter<<<(E_ + 255) / 256, 256, 0, stream>>>(src, dst, ew, dis, cursor, ssrc, sw);
    k_prepw<<<(131072 + (B_ * N_ * C_) / 4 + 255) / 256, 256, 0, stream>>>(
        Wc, W1, W2, x, Wct, W1t, W2t, xbf);
    k_prop<<<N_ / 4 * 8, 256, 0, stream>>>(xbf, offs, ssrc, sw, xbf, Tx1, 0);
    k_prop<<<N_ / 4 * 8, 256, 0, stream>>>(Tx1, offs, ssrc, sw, xbf, Tx2, 1);
    k_fused<<<ROWS_ / 64, 256, 0, stream>>>(x, xbf, Tx1, Tx2, Wct, bc, W1t, b1,
                                            W2t, b2, beta, out);
}

// Round 6
// 262.096 us; speedup vs baseline: 1.0654x; 1.0127x over previous
//
#include <hip/hip_runtime.h>
#include <cstdint>
#include <cstddef>

#define B_ 8
#define N_ 10000
#define C_ 64
#define DIM_ 256
#define E_ 160000
#define ROWS_ (B_ * N_)            // 80000
#define OUT_OFF_ ((size_t)B_ * N_ * C_)  // 5,120,000

typedef unsigned short u16;
typedef unsigned int u32;
typedef __attribute__((ext_vector_type(8))) short bf16x8;
typedef __attribute__((ext_vector_type(4))) float f32x4;

__device__ __forceinline__ u16 f2bf(float f) {
    unsigned int u = __float_as_uint(f);
    unsigned int r = u + 0x7FFF + ((u >> 16) & 1);  // RNE
    return (u16)(r >> 16);
}
__device__ __forceinline__ float bf2f(u32 h) {      // low 16 bits hold bf16
    return __uint_as_float(h << 16);
}
__device__ __forceinline__ unsigned int pack2(float a, float b) {
    return (unsigned int)f2bf(a) | ((unsigned int)f2bf(b) << 16);
}
__device__ __forceinline__ float swish_f(float v, float sp) {
    float e = __expf(-v * sp);
    float s = __builtin_amdgcn_rcpf(1.0f + e);
    return v * s * (1.0f / 1.1f);
}

#define MFMA16(a, b, c) __builtin_amdgcn_mfma_f32_16x16x32_bf16(a, b, c, 0, 0, 0)

// ---- graph preprocessing -------------------------------------------------

__global__ void k_deg(const int* __restrict__ dst, const float* __restrict__ ew,
                      float* __restrict__ deg, int* __restrict__ cnt) {
    int e = blockIdx.x * 256 + threadIdx.x;
    if (e < E_) {
        int d = dst[e];
        atomicAdd(&deg[d], ew[e]);
        atomicAdd(&cnt[d], 1);
    }
}

__global__ void k_dis(const float* __restrict__ deg, float* __restrict__ dis) {
    int n = blockIdx.x * 256 + threadIdx.x;
    if (n < N_) {
        float d = deg[n];
        dis[n] = d > 0.f ? rsqrtf(d) : 0.f;
    }
}

__global__ void k_scan(const int* __restrict__ cnt, int* __restrict__ offs,
                       int* __restrict__ cursor) {
    __shared__ int part[1024];
    int t = threadIdx.x;
    const int CH = 10;
    int base = t * CH;
    int s = 0;
    for (int i = 0; i < CH; i++) {
        int idx = base + i;
        if (idx < N_) s += cnt[idx];
    }
    part[t] = s;
    __syncthreads();
    for (int off = 1; off < 1024; off <<= 1) {
        int v = 0;
        if (t >= off) v = part[t - off];
        __syncthreads();
        if (t >= off) part[t] += v;
        __syncthreads();
    }
    int run = (t > 0) ? part[t - 1] : 0;
    for (int i = 0; i < CH; i++) {
        int idx = base + i;
        if (idx < N_) {
            offs[idx] = run;
            cursor[idx] = run;
            run += cnt[idx];
        }
    }
    if (t == 1023) offs[N_] = run;
}

__global__ void k_scatter(const int* __restrict__ src, const int* __restrict__ dst,
                          const float* __restrict__ ew, const float* __restrict__ dis,
                          int* __restrict__ cursor, int* __restrict__ ssrc,
                          float* __restrict__ sw) {
    int e = blockIdx.x * 256 + threadIdx.x;
    if (e < E_) {
        int sn = src[e], dn = dst[e];
        float w = -(dis[sn] * ew[e] * dis[dn]);
        int p = atomicAdd(&cursor[dn], 1);
        ssrc[p] = sn;
        sw[p] = w;
    }
}

// weight transpose to N-major bf16 + vectorized x cast
__global__ void k_prepw(const float* __restrict__ Wc, const float* __restrict__ W1,
                        const float* __restrict__ W2, const float* __restrict__ x,
                        u16* __restrict__ Wct, u16* __restrict__ W1t,
                        u16* __restrict__ W2t, u16* __restrict__ xbf) {
    int i = blockIdx.x * 256 + threadIdx.x;
    if (i < 49152) {
        int nr = i / 192, k = i % 192;
        Wct[i] = f2bf(Wc[k * 256 + nr]);
    } else if (i < 114688) {
        int j = i - 49152;
        int nr = j >> 8, k = j & 255;
        W1t[j] = f2bf(W1[k * 256 + nr]);
    } else if (i < 131072) {
        int j = i - 114688;
        int nr = j >> 8, k = j & 255;
        W2t[j] = f2bf(W2[k * 64 + nr]);
    } else {
        int j = i - 131072;
        if (j < (B_ * N_ * C_) / 4) {
            float4 v = ((const float4*)x)[j];
            uint2 pv = {pack2(v.x, v.y), pack2(v.z, v.w)};
            ((uint2*)xbf)[j] = pv;
        }
    }
}

// bf16 gather SpMM. One wave per (batch, node); XCD-batch swizzle (b = blk&7).
// mode==1: O = 2*sum - xin  (fused Tx2 computation)
__global__ __launch_bounds__(256) void k_prop(
        const u16* __restrict__ T, const int* __restrict__ offs,
        const int* __restrict__ ssrc, const float* __restrict__ sw,
        const u16* __restrict__ xin, u16* __restrict__ O, int mode) {
    int w = __builtin_amdgcn_readfirstlane(threadIdx.x >> 6);
    int lane = threadIdx.x & 63;
    int b = blockIdx.x & 7;
    int nb = blockIdx.x >> 3;
    int n = nb * 4 + w;
    const u16* Tb = T + (size_t)b * (N_ * C_);
    int s = offs[n], e = offs[n + 1];
    float sum = 0.f;
    int j = s;
    for (; j < e && (j & 3); ++j) sum += bf2f(Tb[(size_t)ssrc[j] * 64 + lane]) * sw[j];
    for (; j + 4 <= e; j += 4) {
        int4 idx = *(const int4*)&ssrc[j];
        float4 wv = *(const float4*)&sw[j];
        sum += bf2f(Tb[(size_t)idx.x * 64 + lane]) * wv.x
             + bf2f(Tb[(size_t)idx.y * 64 + lane]) * wv.y
             + bf2f(Tb[(size_t)idx.z * 64 + lane]) * wv.z
             + bf2f(Tb[(size_t)idx.w * 64 + lane]) * wv.w;
    }
    for (; j < e; ++j) sum += bf2f(Tb[(size_t)ssrc[j] * 64 + lane]) * sw[j];
    size_t g = ((size_t)b * N_ + n) * 64 + lane;
    float v = sum;
    if (mode == 1) v = 2.f * sum - bf2f(xin[g]);
    O[g] = f2bf(v);
}

// ---- fused cheb-einsum + MLP, bf16 MFMA, M=64 rows/block -----------------
// R6: ILP x TLP quadrant. 512 threads (8 waves); for GEMM1/2 wave w owns a
// 32-col N-slice (no B duplication — each weight col loaded once per block);
// GEMM3: wave (w>>2, w&3) owns 32 rows x 16 cols. Keeps R2's 4-deep B
// pipeline + A dbuf. acc shrinks to 4x2 (32 AGPR) so TOTAL unified regs
// (arch + AGPR, the real occupancy currency — R5 post-mortem) fits the
// <=128 tier: 4 waves/SIMD = 16 waves/CU at LDS 33.8KB x 2 blocks.
// __launch_bounds__(512,4): 4 waves/EU = 2 blocks/CU for 512-thr blocks;
// leaves ~96 arch regs — NOT R3's impossible 64 (spill signature: FETCH/
// WRITE jump above 27.5/40 MB).
__global__ __launch_bounds__(512, 4) void k_fused(
        const float* __restrict__ x, const u16* __restrict__ xbf,
        const u16* __restrict__ Tx1, const u16* __restrict__ Tx2,
        const u16* __restrict__ Wct, const float* __restrict__ bc,
        const u16* __restrict__ W1t, const float* __restrict__ b1,
        const u16* __restrict__ W2t, const float* __restrict__ b2,
        const float* __restrict__ beta, float* __restrict__ out) {
    __shared__ u16 buf[64 * 264];   // A0 (cols 0..191) -> h (0..255) -> h2
    int t = threadIdx.x;

    // stage A0 = [xbf | Tx1 | Tx2] bf16, row-major, K-stride 264
    {
        size_t base = (size_t)blockIdx.x * 1024;  // uint2 units (64 rows x 16)
        const uint2* xb = (const uint2*)xbf + base;
        const uint2* tb = (const uint2*)Tx1 + base;
        const uint2* pb = (const uint2*)Tx2 + base;
#pragma unroll
        for (int rep = 0; rep < 2; ++rep) {
            int p = t + rep * 512;
            int r = p >> 4, c4 = p & 15;
            *(uint2*)&buf[r * 264 + c4 * 4] = xb[p];
            *(uint2*)&buf[r * 264 + 64 + c4 * 4] = tb[p];
            *(uint2*)&buf[r * 264 + 128 + c4 * 4] = pb[p];
        }
    }
    __syncthreads();

    float sp = logf(1.f + expf(beta[0]));
    int lane = t & 63, w = t >> 6;
    int m = lane & 15, quad = lane >> 4;
    int q8 = quad * 8;

    // ---- GEMM1: h = A0[64x192] @ Wc[192x256], +bc, swish (regs -> buf)
    {
        f32x4 acc[4][2] = {};
        bf16x8 bfr[4][2];   // rolling 4-deep B pipeline, 2 col-tiles
        bf16x8 afr[2][4];   // A double-buffer, all 4 m-tiles
        const u16* Wp = Wct + (w * 32 + m) * 192 + q8;
#pragma unroll
        for (int d = 0; d < 4; ++d)
#pragma unroll
            for (int nt = 0; nt < 2; ++nt)
                bfr[d][nt] = *(const bf16x8*)(Wp + nt * 16 * 192 + d * 32);
#pragma unroll
        for (int r = 0; r < 4; ++r)
            afr[0][r] = *(const bf16x8*)&buf[(r * 16 + m) * 264 + q8];
#pragma unroll
        for (int kc = 0; kc < 6; ++kc) {
            if (kc < 5) {
                int koff2 = (kc + 1) * 32 + q8;
#pragma unroll
                for (int r = 0; r < 4; ++r)
                    afr[(kc + 1) & 1][r] = *(const bf16x8*)&buf[(r * 16 + m) * 264 + koff2];
            }
#pragma unroll
            for (int nt = 0; nt < 2; ++nt) {
                acc[0][nt] = MFMA16(afr[kc & 1][0], bfr[kc & 3][nt], acc[0][nt]);
                acc[1][nt] = MFMA16(afr[kc & 1][1], bfr[kc & 3][nt], acc[1][nt]);
                acc[2][nt] = MFMA16(afr[kc & 1][2], bfr[kc & 3][nt], acc[2][nt]);
                acc[3][nt] = MFMA16(afr[kc & 1][3], bfr[kc & 3][nt], acc[3][nt]);
            }
            if (kc + 4 < 6) {
#pragma unroll
                for (int nt = 0; nt < 2; ++nt)
                    bfr[kc & 3][nt] = *(const bf16x8*)(Wp + nt * 16 * 192 + (kc + 4) * 32);
            }
        }
        __syncthreads();   // all waves done reading A0; safe to overwrite
#pragma unroll
        for (int mt = 0; mt < 4; ++mt)
#pragma unroll
            for (int nt = 0; nt < 2; ++nt) {
                int col = w * 32 + nt * 16 + m;
                float bcv = bc[col];
#pragma unroll
                for (int i = 0; i < 4; ++i) {
                    int row = mt * 16 + quad * 4 + i;
                    buf[row * 264 + col] = f2bf(swish_f(acc[mt][nt][i] + bcv, sp));
                }
            }
    }
    __syncthreads();

    // ---- GEMM2: h2 = A1[64x256] @ W1[256x256], +b1, swish (regs -> buf)
    {
        f32x4 acc[4][2] = {};
        bf16x8 bfr[4][2];
        bf16x8 afr[2][4];
        const u16* Wp = W1t + (w * 32 + m) * 256 + q8;
#pragma unroll
        for (int d = 0; d < 4; ++d)
#pragma unroll
            for (int nt = 0; nt < 2; ++nt)
                bfr[d][nt] = *(const bf16x8*)(Wp + nt * 16 * 256 + d * 32);
#pragma unroll
        for (int r = 0; r < 4; ++r)
            afr[0][r] = *(const bf16x8*)&buf[(r * 16 + m) * 264 + q8];
#pragma unroll
        for (int kc = 0; kc < 8; ++kc) {
            if (kc < 7) {
                int koff2 = (kc + 1) * 32 + q8;
#pragma unroll
                for (int r = 0; r < 4; ++r)
                    afr[(kc + 1) & 1][r] = *(const bf16x8*)&buf[(r * 16 + m) * 264 + koff2];
            }
#pragma unroll
            for (int nt = 0; nt < 2; ++nt) {
                acc[0][nt] = MFMA16(afr[kc & 1][0], bfr[kc & 3][nt], acc[0][nt]);
                acc[1][nt] = MFMA16(afr[kc & 1][1], bfr[kc & 3][nt], acc[1][nt]);
                acc[2][nt] = MFMA16(afr[kc & 1][2], bfr[kc & 3][nt], acc[2][nt]);
                acc[3][nt] = MFMA16(afr[kc & 1][3], bfr[kc & 3][nt], acc[3][nt]);
            }
            if (kc + 4 < 8) {
#pragma unroll
                for (int nt = 0; nt < 2; ++nt)
                    bfr[kc & 3][nt] = *(const bf16x8*)(Wp + nt * 16 * 256 + (kc + 4) * 32);
            }
        }
        __syncthreads();   // all waves done reading h; safe to overwrite
#pragma unroll
        for (int mt = 0; mt < 4; ++mt)
#pragma unroll
            for (int nt = 0; nt < 2; ++nt) {
                int col = w * 32 + nt * 16 + m;
                float b1v = b1[col];
#pragma unroll
                for (int i = 0; i < 4; ++i) {
                    int row = mt * 16 + quad * 4 + i;
                    buf[row * 264 + col] = f2bf(swish_f(acc[mt][nt][i] + b1v, sp));
                }
            }
    }
    __syncthreads();

    // ---- GEMM3: Fx = A2[64x256] @ W2[256x64], +b2; out = Fx + x, Fx
    // wave (wm3 = w>>2, wn3 = w&3): rows wm3*32..+32, cols wn3*16..+16
    {
        int wm3 = w >> 2, wn3 = w & 3;
        int rb3 = wm3 * 32;
        f32x4 acc3[2] = {};
        bf16x8 bfr[8];      // whole B panel preloaded (8 x 16B = 32 VGPR)
        bf16x8 afr[2][2];
        const u16* Wp = W2t + (wn3 * 16 + m) * 256 + q8;
#pragma unroll
        for (int d = 0; d < 8; ++d) bfr[d] = *(const bf16x8*)(Wp + d * 32);
#pragma unroll
        for (int r = 0; r < 2; ++r)
            afr[0][r] = *(const bf16x8*)&buf[(rb3 + r * 16 + m) * 264 + q8];
#pragma unroll
        for (int kc = 0; kc < 8; ++kc) {
            if (kc < 7) {
                int koff2 = (kc + 1) * 32 + q8;
#pragma unroll
                for (int r = 0; r < 2; ++r)
                    afr[(kc + 1) & 1][r] = *(const bf16x8*)&buf[(rb3 + r * 16 + m) * 264 + koff2];
            }
            acc3[0] = MFMA16(afr[kc & 1][0], bfr[kc], acc3[0]);
            acc3[1] = MFMA16(afr[kc & 1][1], bfr[kc], acc3[1]);
        }
        int col = wn3 * 16 + m;
        float b2v = b2[col];
#pragma unroll
        for (int mt = 0; mt < 2; ++mt)
#pragma unroll
            for (int i = 0; i < 4; ++i) {
                int row = rb3 + mt * 16 + quad * 4 + i;
                size_t g = ((size_t)blockIdx.x * 64 + row) * 64 + col;
                float f = acc3[mt][i] + b2v;
                out[g] = f + x[g];
                out[OUT_OFF_ + g] = f;
            }
    }
}

extern "C" void kernel_launch(void* const* d_in, const int* in_sizes, int n_in,
                              void* d_out, int out_size, void* d_ws, size_t ws_size,
                              hipStream_t stream) {
    const float* x    = (const float*)d_in[0];
    const float* ew   = (const float*)d_in[1];
    const float* Wc   = (const float*)d_in[2];
    const float* bc   = (const float*)d_in[3];
    const float* W1   = (const float*)d_in[4];
    const float* b1   = (const float*)d_in[5];
    const float* W2   = (const float*)d_in[6];
    const float* b2   = (const float*)d_in[7];
    const float* beta = (const float*)d_in[8];
    const int*   ei   = (const int*)d_in[9];
    const int* src = ei;
    const int* dst = ei + E_;
    float* out = (float*)d_out;

    // workspace layout (float units)
    float* ws = (float*)d_ws;
    float* deg    = ws + 0;                 // N
    float* dis    = ws + 10000;             // N
    int*   cnt    = (int*)(ws + 20000);     // N
    int*   offs   = (int*)(ws + 30000);     // N+1 (pad to 10008)
    int*   cursor = (int*)(ws + 40008);     // N
    int*   ssrc   = (int*)(ws + 50008);     // E
    float* sw     = ws + 210008;            // E
    u16*   xbf    = (u16*)(ws + 370008);    // B*N*C u16
    u16*   Tx1    = (u16*)(ws + 2930008);   // B*N*C u16
    u16*   Tx2    = (u16*)(ws + 5490008);   // B*N*C u16
    u16*   Wct    = (u16*)(ws + 8050008);   // 49152 u16
    u16*   W1t    = (u16*)(ws + 8074584);   // 65536 u16
    u16*   W2t    = (u16*)(ws + 8107352);   // 16384 u16

    hipMemsetAsync(deg, 0, (size_t)N_ * sizeof(float), stream);
    hipMemsetAsync(cnt, 0, (size_t)N_ * sizeof(int), stream);

    k_deg<<<(E_ + 255) / 256, 256, 0, stream>>>(dst, ew, deg, cnt);
    k_dis<<<(N_ + 255) / 256, 256, 0, stream>>>(deg, dis);
    k_scan<<<1, 1024, 0, stream>>>(cnt, offs, cursor);
    k_scatter<<<(E_ + 255) / 256, 256, 0, stream>>>(src, dst, ew, dis, cursor, ssrc, sw);
    k_prepw<<<(131072 + (B_ * N_ * C_) / 4 + 255) / 256, 256, 0, stream>>>(
        Wc, W1, W2, x, Wct, W1t, W2t, xbf);
    k_prop<<<N_ / 4 * 8, 256, 0, stream>>>(xbf, offs, ssrc, sw, xbf, Tx1, 0);
    k_prop<<<N_ / 4 * 8, 256, 0, stream>>>(Tx1, offs, ssrc, sw, xbf, Tx2, 1);
    k_fused<<<ROWS_ / 64, 512, 0, stream>>>(x, xbf, Tx1, Tx2, Wct, bc, W1t, b1,
                                            W2t, b2, beta, out);
}

// Round 7
// 247.896 us; speedup vs baseline: 1.1264x; 1.0573x over previous
//
#include <hip/hip_runtime.h>
#include <cstdint>
#include <cstddef>

#define B_ 8
#define N_ 10000
#define C_ 64
#define DIM_ 256
#define E_ 160000
#define ROWS_ (B_ * N_)            // 80000
#define OUT_OFF_ ((size_t)B_ * N_ * C_)  // 5,120,000

typedef unsigned short u16;
typedef unsigned int u32;
typedef __attribute__((ext_vector_type(8))) short bf16x8;
typedef __attribute__((ext_vector_type(4))) float f32x4;

__device__ __forceinline__ u16 f2bf(float f) {
    unsigned int u = __float_as_uint(f);
    unsigned int r = u + 0x7FFF + ((u >> 16) & 1);  // RNE
    return (u16)(r >> 16);
}
__device__ __forceinline__ float bf2f(u32 h) {      // low 16 bits hold bf16
    return __uint_as_float(h << 16);
}
__device__ __forceinline__ unsigned int pack2(float a, float b) {
    return (unsigned int)f2bf(a) | ((unsigned int)f2bf(b) << 16);
}
__device__ __forceinline__ float swish_f(float v, float sp) {
    float e = __expf(-v * sp);
    float s = __builtin_amdgcn_rcpf(1.0f + e);
    return v * s * (1.0f / 1.1f);
}

#define MFMA16(a, b, c) __builtin_amdgcn_mfma_f32_16x16x32_bf16(a, b, c, 0, 0, 0)

// ---- graph preprocessing -------------------------------------------------

__global__ void k_deg(const int* __restrict__ dst, const float* __restrict__ ew,
                      float* __restrict__ deg, int* __restrict__ cnt) {
    int e = blockIdx.x * 256 + threadIdx.x;
    if (e < E_) {
        int d = dst[e];
        atomicAdd(&deg[d], ew[e]);
        atomicAdd(&cnt[d], 1);
    }
}

__global__ void k_dis(const float* __restrict__ deg, float* __restrict__ dis) {
    int n = blockIdx.x * 256 + threadIdx.x;
    if (n < N_) {
        float d = deg[n];
        dis[n] = d > 0.f ? rsqrtf(d) : 0.f;
    }
}

__global__ void k_scan(const int* __restrict__ cnt, int* __restrict__ offs,
                       int* __restrict__ cursor) {
    __shared__ int part[1024];
    int t = threadIdx.x;
    const int CH = 10;
    int base = t * CH;
    int s = 0;
    for (int i = 0; i < CH; i++) {
        int idx = base + i;
        if (idx < N_) s += cnt[idx];
    }
    part[t] = s;
    __syncthreads();
    for (int off = 1; off < 1024; off <<= 1) {
        int v = 0;
        if (t >= off) v = part[t - off];
        __syncthreads();
        if (t >= off) part[t] += v;
        __syncthreads();
    }
    int run = (t > 0) ? part[t - 1] : 0;
    for (int i = 0; i < CH; i++) {
        int idx = base + i;
        if (idx < N_) {
            offs[idx] = run;
            cursor[idx] = run;
            run += cnt[idx];
        }
    }
    if (t == 1023) offs[N_] = run;
}

__global__ void k_scatter(const int* __restrict__ src, const int* __restrict__ dst,
                          const float* __restrict__ ew, const float* __restrict__ dis,
                          int* __restrict__ cursor, int* __restrict__ ssrc,
                          float* __restrict__ sw) {
    int e = blockIdx.x * 256 + threadIdx.x;
    if (e < E_) {
        int sn = src[e], dn = dst[e];
        float w = -(dis[sn] * ew[e] * dis[dn]);
        int p = atomicAdd(&cursor[dn], 1);
        ssrc[p] = sn;
        sw[p] = w;
    }
}

// weight transpose to N-major bf16 + x cast into GATHER layout [n][b][c]
__global__ void k_prepw(const float* __restrict__ Wc, const float* __restrict__ W1,
                        const float* __restrict__ W2, const float* __restrict__ x,
                        u16* __restrict__ Wct, u16* __restrict__ W1t,
                        u16* __restrict__ W2t, u16* __restrict__ xg) {
    int i = blockIdx.x * 256 + threadIdx.x;
    if (i < 49152) {
        int nr = i / 192, k = i % 192;
        Wct[i] = f2bf(Wc[k * 256 + nr]);
    } else if (i < 114688) {
        int j = i - 49152;
        int nr = j >> 8, k = j & 255;
        W1t[j] = f2bf(W1[k * 256 + nr]);
    } else if (i < 131072) {
        int j = i - 114688;
        int nr = j >> 8, k = j & 255;
        W2t[j] = f2bf(W2[k * 64 + nr]);
    } else {
        int j = i - 131072;
        if (j < (B_ * N_ * C_) / 4) {
            float4 v = ((const float4*)x)[j];
            int flat4 = j * 4;                 // [b][n][c] flat f32 index
            int b = flat4 / (N_ * C_);
            int rem = flat4 - b * (N_ * C_);
            int n = rem >> 6, c = rem & 63;
            uint2 pv = {pack2(v.x, v.y), pack2(v.z, v.w)};
            *(uint2*)(xg + (size_t)n * 512 + b * 64 + c) = pv;
        }
    }
}

// R7: batch-merged gather SpMM on [n][b][c] layout. One wave per NODE; per
// edge the wave reads one CONTIGUOUS 1 KB row (all 8 batches x 64 ch) as
// lane-striped dwordx4 — replaces 8 scattered 128-B gathers + 8x edge-meta
// re-reads of the old per-(b,n) kernel. Lane l owns (b = l>>3, c = (l&7)*8..+8),
// 8 f32 accumulators. mode==1: O = 2*sum - xg_row (fused Tx2).
__global__ __launch_bounds__(256) void k_prop_g(
        const u16* __restrict__ Tg, const int* __restrict__ offs,
        const int* __restrict__ ssrc, const float* __restrict__ sw,
        const u16* __restrict__ xg, u16* __restrict__ Og, int mode) {
    int w = __builtin_amdgcn_readfirstlane(threadIdx.x >> 6);
    int lane = threadIdx.x & 63;
    int n = blockIdx.x * 4 + w;
    int s = offs[n], e = offs[n + 1];
    int lo = lane * 8;
    float sum[8] = {};
    int j = s;
    for (; j < e && (j & 3); ++j) {
        int idx = ssrc[j];
        float wv = sw[j];
        bf16x8 v = *(const bf16x8*)(Tg + (size_t)idx * 512 + lo);
#pragma unroll
        for (int k = 0; k < 8; ++k) sum[k] += bf2f((u16)v[k]) * wv;
    }
    for (; j + 4 <= e; j += 4) {
        int4 idx = *(const int4*)&ssrc[j];
        float4 wv = *(const float4*)&sw[j];
        bf16x8 v0 = *(const bf16x8*)(Tg + (size_t)idx.x * 512 + lo);
        bf16x8 v1 = *(const bf16x8*)(Tg + (size_t)idx.y * 512 + lo);
        bf16x8 v2 = *(const bf16x8*)(Tg + (size_t)idx.z * 512 + lo);
        bf16x8 v3 = *(const bf16x8*)(Tg + (size_t)idx.w * 512 + lo);
#pragma unroll
        for (int k = 0; k < 8; ++k)
            sum[k] += bf2f((u16)v0[k]) * wv.x + bf2f((u16)v1[k]) * wv.y
                    + bf2f((u16)v2[k]) * wv.z + bf2f((u16)v3[k]) * wv.w;
    }
    for (; j < e; ++j) {
        int idx = ssrc[j];
        float wv = sw[j];
        bf16x8 v = *(const bf16x8*)(Tg + (size_t)idx * 512 + lo);
#pragma unroll
        for (int k = 0; k < 8; ++k) sum[k] += bf2f((u16)v[k]) * wv;
    }
    size_t go = (size_t)n * 512 + lo;
    bf16x8 o;
    if (mode == 1) {
        bf16x8 xv = *(const bf16x8*)(xg + go);
#pragma unroll
        for (int k = 0; k < 8; ++k) o[k] = (short)f2bf(2.f * sum[k] - bf2f((u16)xv[k]));
    } else {
#pragma unroll
        for (int k = 0; k < 8; ++k) o[k] = (short)f2bf(sum[k]);
    }
    *(bf16x8*)(Og + go) = o;
}

// ---- fused cheb-einsum + MLP, bf16 MFMA, M=64 rows/block -----------------
// R6 structure kept (ILP x TLP: 512 thr, 8 waves, 32-col N-slices, 4-deep B
// pipeline, single 33.8 KB LDS buffer, occ 35%). R7 change: A0 staged from
// gather-layout Tx1g/Tx2g ([n][b][c]) with per-row (b,n) derivation (blocks
// span batch boundaries), and x converted f32->bf16 in staging (xbf dead).
__global__ __launch_bounds__(512, 4) void k_fused(
        const float* __restrict__ x,
        const u16* __restrict__ Tx1g, const u16* __restrict__ Tx2g,
        const u16* __restrict__ Wct, const float* __restrict__ bc,
        const u16* __restrict__ W1t, const float* __restrict__ b1,
        const u16* __restrict__ W2t, const float* __restrict__ b2,
        const float* __restrict__ beta, float* __restrict__ out) {
    __shared__ u16 buf[64 * 264];   // A0 (cols 0..191) -> h (0..255) -> h2
    int t = threadIdx.x;

    // stage A0 = [x | Tx1 | Tx2] bf16, row-major, K-stride 264
    {
        int r = t >> 3, seg = t & 7;            // 64 rows x 8 segs of 16 B
        size_t g = (size_t)blockIdx.x * 64 + r;
        int b = (int)(g / N_), n = (int)(g % N_);
        size_t go = (size_t)n * 512 + b * 64 + seg * 8;
        const float4* xf = (const float4*)(x + g * 64 + seg * 8);
        float4 x0 = xf[0], x1 = xf[1];
        bf16x8 t1 = *(const bf16x8*)(Tx1g + go);
        bf16x8 t2 = *(const bf16x8*)(Tx2g + go);
        uint4 xp;
        xp.x = pack2(x0.x, x0.y); xp.y = pack2(x0.z, x0.w);
        xp.z = pack2(x1.x, x1.y); xp.w = pack2(x1.z, x1.w);
        *(uint4*)&buf[r * 264 + seg * 8] = xp;
        *(bf16x8*)&buf[r * 264 + 64 + seg * 8] = t1;
        *(bf16x8*)&buf[r * 264 + 128 + seg * 8] = t2;
    }
    __syncthreads();

    float sp = logf(1.f + expf(beta[0]));
    int lane = t & 63, w = t >> 6;
    int m = lane & 15, quad = lane >> 4;
    int q8 = quad * 8;

    // ---- GEMM1: h = A0[64x192] @ Wc[192x256], +bc, swish (regs -> buf)
    {
        f32x4 acc[4][2] = {};
        bf16x8 bfr[4][2];   // rolling 4-deep B pipeline, 2 col-tiles
        bf16x8 afr[2][4];   // A double-buffer, all 4 m-tiles
        const u16* Wp = Wct + (w * 32 + m) * 192 + q8;
#pragma unroll
        for (int d = 0; d < 4; ++d)
#pragma unroll
            for (int nt = 0; nt < 2; ++nt)
                bfr[d][nt] = *(const bf16x8*)(Wp + nt * 16 * 192 + d * 32);
#pragma unroll
        for (int r = 0; r < 4; ++r)
            afr[0][r] = *(const bf16x8*)&buf[(r * 16 + m) * 264 + q8];
#pragma unroll
        for (int kc = 0; kc < 6; ++kc) {
            if (kc < 5) {
                int koff2 = (kc + 1) * 32 + q8;
#pragma unroll
                for (int r = 0; r < 4; ++r)
                    afr[(kc + 1) & 1][r] = *(const bf16x8*)&buf[(r * 16 + m) * 264 + koff2];
            }
#pragma unroll
            for (int nt = 0; nt < 2; ++nt) {
                acc[0][nt] = MFMA16(afr[kc & 1][0], bfr[kc & 3][nt], acc[0][nt]);
                acc[1][nt] = MFMA16(afr[kc & 1][1], bfr[kc & 3][nt], acc[1][nt]);
                acc[2][nt] = MFMA16(afr[kc & 1][2], bfr[kc & 3][nt], acc[2][nt]);
                acc[3][nt] = MFMA16(afr[kc & 1][3], bfr[kc & 3][nt], acc[3][nt]);
            }
            if (kc + 4 < 6) {
#pragma unroll
                for (int nt = 0; nt < 2; ++nt)
                    bfr[kc & 3][nt] = *(const bf16x8*)(Wp + nt * 16 * 192 + (kc + 4) * 32);
            }
        }
        __syncthreads();   // all waves done reading A0; safe to overwrite
#pragma unroll
        for (int mt = 0; mt < 4; ++mt)
#pragma unroll
            for (int nt = 0; nt < 2; ++nt) {
                int col = w * 32 + nt * 16 + m;
                float bcv = bc[col];
#pragma unroll
                for (int i = 0; i < 4; ++i) {
                    int row = mt * 16 + quad * 4 + i;
                    buf[row * 264 + col] = f2bf(swish_f(acc[mt][nt][i] + bcv, sp));
                }
            }
    }
    __syncthreads();

    // ---- GEMM2: h2 = A1[64x256] @ W1[256x256], +b1, swish (regs -> buf)
    {
        f32x4 acc[4][2] = {};
        bf16x8 bfr[4][2];
        bf16x8 afr[2][4];
        const u16* Wp = W1t + (w * 32 + m) * 256 + q8;
#pragma unroll
        for (int d = 0; d < 4; ++d)
#pragma unroll
            for (int nt = 0; nt < 2; ++nt)
                bfr[d][nt] = *(const bf16x8*)(Wp + nt * 16 * 256 + d * 32);
#pragma unroll
        for (int r = 0; r < 4; ++r)
            afr[0][r] = *(const bf16x8*)&buf[(r * 16 + m) * 264 + q8];
#pragma unroll
        for (int kc = 0; kc < 8; ++kc) {
            if (kc < 7) {
                int koff2 = (kc + 1) * 32 + q8;
#pragma unroll
                for (int r = 0; r < 4; ++r)
                    afr[(kc + 1) & 1][r] = *(const bf16x8*)&buf[(r * 16 + m) * 264 + koff2];
            }
#pragma unroll
            for (int nt = 0; nt < 2; ++nt) {
                acc[0][nt] = MFMA16(afr[kc & 1][0], bfr[kc & 3][nt], acc[0][nt]);
                acc[1][nt] = MFMA16(afr[kc & 1][1], bfr[kc & 3][nt], acc[1][nt]);
                acc[2][nt] = MFMA16(afr[kc & 1][2], bfr[kc & 3][nt], acc[2][nt]);
                acc[3][nt] = MFMA16(afr[kc & 1][3], bfr[kc & 3][nt], acc[3][nt]);
            }
            if (kc + 4 < 8) {
#pragma unroll
                for (int nt = 0; nt < 2; ++nt)
                    bfr[kc & 3][nt] = *(const bf16x8*)(Wp + nt * 16 * 256 + (kc + 4) * 32);
            }
        }
        __syncthreads();   // all waves done reading h; safe to overwrite
#pragma unroll
        for (int mt = 0; mt < 4; ++mt)
#pragma unroll
            for (int nt = 0; nt < 2; ++nt) {
                int col = w * 32 + nt * 16 + m;
                float b1v = b1[col];
#pragma unroll
                for (int i = 0; i < 4; ++i) {
                    int row = mt * 16 + quad * 4 + i;
                    buf[row * 264 + col] = f2bf(swish_f(acc[mt][nt][i] + b1v, sp));
                }
            }
    }
    __syncthreads();

    // ---- GEMM3: Fx = A2[64x256] @ W2[256x64], +b2; out = Fx + x, Fx
    // wave (wm3 = w>>2, wn3 = w&3): rows wm3*32..+32, cols wn3*16..+16
    {
        int wm3 = w >> 2, wn3 = w & 3;
        int rb3 = wm3 * 32;
        f32x4 acc3[2] = {};
        bf16x8 bfr[8];      // whole B panel preloaded (8 x 16B = 32 VGPR)
        bf16x8 afr[2][2];
        const u16* Wp = W2t + (wn3 * 16 + m) * 256 + q8;
#pragma unroll
        for (int d = 0; d < 8; ++d) bfr[d] = *(const bf16x8*)(Wp + d * 32);
#pragma unroll
        for (int r = 0; r < 2; ++r)
            afr[0][r] = *(const bf16x8*)&buf[(rb3 + r * 16 + m) * 264 + q8];
#pragma unroll
        for (int kc = 0; kc < 8; ++kc) {
            if (kc < 7) {
                int koff2 = (kc + 1) * 32 + q8;
#pragma unroll
                for (int r = 0; r < 2; ++r)
                    afr[(kc + 1) & 1][r] = *(const bf16x8*)&buf[(rb3 + r * 16 + m) * 264 + koff2];
            }
            acc3[0] = MFMA16(afr[kc & 1][0], bfr[kc], acc3[0]);
            acc3[1] = MFMA16(afr[kc & 1][1], bfr[kc], acc3[1]);
        }
        int col = wn3 * 16 + m;
        float b2v = b2[col];
#pragma unroll
        for (int mt = 0; mt < 2; ++mt)
#pragma unroll
            for (int i = 0; i < 4; ++i) {
                int row = rb3 + mt * 16 + quad * 4 + i;
                size_t g = ((size_t)blockIdx.x * 64 + row) * 64 + col;
                float f = acc3[mt][i] + b2v;
                out[g] = f + x[g];
                out[OUT_OFF_ + g] = f;
            }
    }
}

extern "C" void kernel_launch(void* const* d_in, const int* in_sizes, int n_in,
                              void* d_out, int out_size, void* d_ws, size_t ws_size,
                              hipStream_t stream) {
    const float* x    = (const float*)d_in[0];
    const float* ew   = (const float*)d_in[1];
    const float* Wc   = (const float*)d_in[2];
    const float* bc   = (const float*)d_in[3];
    const float* W1   = (const float*)d_in[4];
    const float* b1   = (const float*)d_in[5];
    const float* W2   = (const float*)d_in[6];
    const float* b2   = (const float*)d_in[7];
    const float* beta = (const float*)d_in[8];
    const int*   ei   = (const int*)d_in[9];
    const int* src = ei;
    const int* dst = ei + E_;
    float* out = (float*)d_out;

    // workspace layout (float units)
    float* ws = (float*)d_ws;
    float* deg    = ws + 0;                 // N
    float* dis    = ws + 10000;             // N
    int*   cnt    = (int*)(ws + 20000);     // N
    int*   offs   = (int*)(ws + 30000);     // N+1 (pad to 10008)
    int*   cursor = (int*)(ws + 40008);     // N
    int*   ssrc   = (int*)(ws + 50008);     // E
    float* sw     = ws + 210008;            // E
    u16*   xg     = (u16*)(ws + 370008);    // [n][b][c] B*N*C u16
    u16*   Tx1g   = (u16*)(ws + 2930008);   // [n][b][c] B*N*C u16
    u16*   Tx2g   = (u16*)(ws + 5490008);   // [n][b][c] B*N*C u16
    u16*   Wct    = (u16*)(ws + 8050008);   // 49152 u16
    u16*   W1t    = (u16*)(ws + 8074584);   // 65536 u16
    u16*   W2t    = (u16*)(ws + 8107352);   // 16384 u16

    hipMemsetAsync(deg, 0, (size_t)N_ * sizeof(float), stream);
    hipMemsetAsync(cnt, 0, (size_t)N_ * sizeof(int), stream);

    k_deg<<<(E_ + 255) / 256, 256, 0, stream>>>(dst, ew, deg, cnt);
    k_dis<<<(N_ + 255) / 256, 256, 0, stream>>>(deg, dis);
    k_scan<<<1, 1024, 0, stream>>>(cnt, offs, cursor);
    k_scatter<<<(E_ + 255) / 256, 256, 0, stream>>>(src, dst, ew, dis, cursor, ssrc, sw);
    k_prepw<<<(131072 + (B_ * N_ * C_) / 4 + 255) / 256, 256, 0, stream>>>(
        Wc, W1, W2, x, Wct, W1t, W2t, xg);
    k_prop_g<<<N_ / 4, 256, 0, stream>>>(xg, offs, ssrc, sw, xg, Tx1g, 0);
    k_prop_g<<<N_ / 4, 256, 0, stream>>>(Tx1g, offs, ssrc, sw, xg, Tx2g, 1);
    k_fused<<<ROWS_ / 64, 512, 0, stream>>>(x, Tx1g, Tx2g, Wct, bc, W1t, b1,
                                            W2t, b2, beta, out);
}

// Round 8
// 243.519 us; speedup vs baseline: 1.1467x; 1.0180x over previous
//
#include <hip/hip_runtime.h>
#include <cstdint>
#include <cstddef>

#define B_ 8
#define N_ 10000
#define C_ 64
#define DIM_ 256
#define E_ 160000
#define ROWS_ (B_ * N_)            // 80000
#define OUT_OFF_ ((size_t)B_ * N_ * C_)  // 5,120,000

typedef unsigned short u16;
typedef unsigned int u32;
typedef __attribute__((ext_vector_type(8))) short bf16x8;
typedef __attribute__((ext_vector_type(4))) float f32x4;

__device__ __forceinline__ u16 f2bf(float f) {
    unsigned int u = __float_as_uint(f);
    unsigned int r = u + 0x7FFF + ((u >> 16) & 1);  // RNE
    return (u16)(r >> 16);
}
__device__ __forceinline__ float bf2f(u32 h) {      // low 16 bits hold bf16
    return __uint_as_float(h << 16);
}
__device__ __forceinline__ unsigned int pack2(float a, float b) {
    return (unsigned int)f2bf(a) | ((unsigned int)f2bf(b) << 16);
}
__device__ __forceinline__ float swish_f(float v, float sp) {
    float e = __expf(-v * sp);
    float s = __builtin_amdgcn_rcpf(1.0f + e);
    return v * s * (1.0f / 1.1f);
}

#define MFMA16(a, b, c) __builtin_amdgcn_mfma_f32_16x16x32_bf16(a, b, c, 0, 0, 0)

// ---- graph preprocessing -------------------------------------------------

__global__ void k_deg(const int* __restrict__ dst, const float* __restrict__ ew,
                      float* __restrict__ deg, int* __restrict__ cnt) {
    int e = blockIdx.x * 256 + threadIdx.x;
    if (e < E_) {
        int d = dst[e];
        atomicAdd(&deg[d], ew[e]);
        atomicAdd(&cnt[d], 1);
    }
}

__global__ void k_dis(const float* __restrict__ deg, float* __restrict__ dis) {
    int n = blockIdx.x * 256 + threadIdx.x;
    if (n < N_) {
        float d = deg[n];
        dis[n] = d > 0.f ? rsqrtf(d) : 0.f;
    }
}

__global__ void k_scan(const int* __restrict__ cnt, int* __restrict__ offs,
                       int* __restrict__ cursor) {
    __shared__ int part[1024];
    int t = threadIdx.x;
    const int CH = 10;
    int base = t * CH;
    int s = 0;
    for (int i = 0; i < CH; i++) {
        int idx = base + i;
        if (idx < N_) s += cnt[idx];
    }
    part[t] = s;
    __syncthreads();
    for (int off = 1; off < 1024; off <<= 1) {
        int v = 0;
        if (t >= off) v = part[t - off];
        __syncthreads();
        if (t >= off) part[t] += v;
        __syncthreads();
    }
    int run = (t > 0) ? part[t - 1] : 0;
    for (int i = 0; i < CH; i++) {
        int idx = base + i;
        if (idx < N_) {
            offs[idx] = run;
            cursor[idx] = run;
            run += cnt[idx];
        }
    }
    if (t == 1023) offs[N_] = run;
}

__global__ void k_scatter(const int* __restrict__ src, const int* __restrict__ dst,
                          const float* __restrict__ ew, const float* __restrict__ dis,
                          int* __restrict__ cursor, int* __restrict__ ssrc,
                          float* __restrict__ sw) {
    int e = blockIdx.x * 256 + threadIdx.x;
    if (e < E_) {
        int sn = src[e], dn = dst[e];
        float w = -(dis[sn] * ew[e] * dis[dn]);
        int p = atomicAdd(&cursor[dn], 1);
        ssrc[p] = sn;
        sw[p] = w;
    }
}

// weight transpose to N-major bf16 + x cast into GATHER layout [n][b][c]
__global__ void k_prepw(const float* __restrict__ Wc, const float* __restrict__ W1,
                        const float* __restrict__ W2, const float* __restrict__ x,
                        u16* __restrict__ Wct, u16* __restrict__ W1t,
                        u16* __restrict__ W2t, u16* __restrict__ xg) {
    int i = blockIdx.x * 256 + threadIdx.x;
    if (i < 49152) {
        int nr = i / 192, k = i % 192;
        Wct[i] = f2bf(Wc[k * 256 + nr]);
    } else if (i < 114688) {
        int j = i - 49152;
        int nr = j >> 8, k = j & 255;
        W1t[j] = f2bf(W1[k * 256 + nr]);
    } else if (i < 131072) {
        int j = i - 114688;
        int nr = j >> 8, k = j & 255;
        W2t[j] = f2bf(W2[k * 64 + nr]);
    } else {
        int j = i - 131072;
        if (j < (B_ * N_ * C_) / 4) {
            float4 v = ((const float4*)x)[j];
            int flat4 = j * 4;                 // [b][n][c] flat f32 index
            int b = flat4 / (N_ * C_);
            int rem = flat4 - b * (N_ * C_);
            int n = rem >> 6, c = rem & 63;
            uint2 pv = {pack2(v.x, v.y), pack2(v.z, v.w)};
            *(uint2*)(xg + (size_t)n * 512 + b * 64 + c) = pv;
        }
    }
}

// R8: batch-merged gather SpMM, edge pipeline deepened 4 -> 8 (avg degree 16
// -> 2 latency rounds instead of 4; prop was ~10x above its BW floor ->
// latency-chain hypothesis). One wave per NODE; per edge one contiguous 1 KB
// row (8 batches x 64 ch), lane l owns (b=l>>3, c=(l&7)*8..+8).
// mode==1: O = 2*sum - xg_row (fused Tx2).
__global__ __launch_bounds__(256) void k_prop_g(
        const u16* __restrict__ Tg, const int* __restrict__ offs,
        const int* __restrict__ ssrc, const float* __restrict__ sw,
        const u16* __restrict__ xg, u16* __restrict__ Og, int mode) {
    int w = __builtin_amdgcn_readfirstlane(threadIdx.x >> 6);
    int lane = threadIdx.x & 63;
    int n = blockIdx.x * 4 + w;
    int s = offs[n], e = offs[n + 1];
    int lo = lane * 8;
    float sum[8] = {};
    int j = s;
    for (; j < e && (j & 3); ++j) {
        int idx = ssrc[j];
        float wv = sw[j];
        bf16x8 v = *(const bf16x8*)(Tg + (size_t)idx * 512 + lo);
#pragma unroll
        for (int k = 0; k < 8; ++k) sum[k] += bf2f((u16)v[k]) * wv;
    }
    for (; j + 8 <= e; j += 8) {
        int4 ia = *(const int4*)&ssrc[j];
        int4 ib = *(const int4*)&ssrc[j + 4];
        float4 wa = *(const float4*)&sw[j];
        float4 wb = *(const float4*)&sw[j + 4];
        bf16x8 v0 = *(const bf16x8*)(Tg + (size_t)ia.x * 512 + lo);
        bf16x8 v1 = *(const bf16x8*)(Tg + (size_t)ia.y * 512 + lo);
        bf16x8 v2 = *(const bf16x8*)(Tg + (size_t)ia.z * 512 + lo);
        bf16x8 v3 = *(const bf16x8*)(Tg + (size_t)ia.w * 512 + lo);
        bf16x8 v4 = *(const bf16x8*)(Tg + (size_t)ib.x * 512 + lo);
        bf16x8 v5 = *(const bf16x8*)(Tg + (size_t)ib.y * 512 + lo);
        bf16x8 v6 = *(const bf16x8*)(Tg + (size_t)ib.z * 512 + lo);
        bf16x8 v7 = *(const bf16x8*)(Tg + (size_t)ib.w * 512 + lo);
#pragma unroll
        for (int k = 0; k < 8; ++k)
            sum[k] += bf2f((u16)v0[k]) * wa.x + bf2f((u16)v1[k]) * wa.y
                    + bf2f((u16)v2[k]) * wa.z + bf2f((u16)v3[k]) * wa.w
                    + bf2f((u16)v4[k]) * wb.x + bf2f((u16)v5[k]) * wb.y
                    + bf2f((u16)v6[k]) * wb.z + bf2f((u16)v7[k]) * wb.w;
    }
    for (; j + 4 <= e; j += 4) {
        int4 idx = *(const int4*)&ssrc[j];
        float4 wv = *(const float4*)&sw[j];
        bf16x8 v0 = *(const bf16x8*)(Tg + (size_t)idx.x * 512 + lo);
        bf16x8 v1 = *(const bf16x8*)(Tg + (size_t)idx.y * 512 + lo);
        bf16x8 v2 = *(const bf16x8*)(Tg + (size_t)idx.z * 512 + lo);
        bf16x8 v3 = *(const bf16x8*)(Tg + (size_t)idx.w * 512 + lo);
#pragma unroll
        for (int k = 0; k < 8; ++k)
            sum[k] += bf2f((u16)v0[k]) * wv.x + bf2f((u16)v1[k]) * wv.y
                    + bf2f((u16)v2[k]) * wv.z + bf2f((u16)v3[k]) * wv.w;
    }
    for (; j < e; ++j) {
        int idx = ssrc[j];
        float wv = sw[j];
        bf16x8 v = *(const bf16x8*)(Tg + (size_t)idx * 512 + lo);
#pragma unroll
        for (int k = 0; k < 8; ++k) sum[k] += bf2f((u16)v[k]) * wv;
    }
    size_t go = (size_t)n * 512 + lo;
    bf16x8 o;
    if (mode == 1) {
        bf16x8 xv = *(const bf16x8*)(xg + go);
#pragma unroll
        for (int k = 0; k < 8; ++k) o[k] = (short)f2bf(2.f * sum[k] - bf2f((u16)xv[k]));
    } else {
#pragma unroll
        for (int k = 0; k < 8; ++k) o[k] = (short)f2bf(sum[k]);
    }
    *(bf16x8*)(Og + go) = o;
}

// ---- fused cheb-einsum + MLP, bf16 MFMA, M=64 rows/block -----------------
// R6 structure kept (ILP x TLP: 512 thr, 8 waves, 32-col N-slices, 4-deep B
// pipeline, single 33.8 KB LDS buffer, occ 35%). R8 change: A0's x-slice
// staged from xg (bf16, same contiguous [n][b][c] row as Tx1g/Tx2g) —
// reverts R7's accidental f32-x staging (+10 MB FETCH, +pack2 VALU, 61->65).
// Epilogue residual still reads f32 x (precision).
__global__ __launch_bounds__(512, 4) void k_fused(
        const float* __restrict__ x, const u16* __restrict__ xg,
        const u16* __restrict__ Tx1g, const u16* __restrict__ Tx2g,
        const u16* __restrict__ Wct, const float* __restrict__ bc,
        const u16* __restrict__ W1t, const float* __restrict__ b1,
        const u16* __restrict__ W2t, const float* __restrict__ b2,
        const float* __restrict__ beta, float* __restrict__ out) {
    __shared__ u16 buf[64 * 264];   // A0 (cols 0..191) -> h (0..255) -> h2
    int t = threadIdx.x;

    // stage A0 = [xg | Tx1g | Tx2g] bf16, row-major, K-stride 264
    {
        int r = t >> 3, seg = t & 7;            // 64 rows x 8 segs of 16 B
        size_t g = (size_t)blockIdx.x * 64 + r;
        int b = (int)(g / N_), n = (int)(g % N_);
        size_t go = (size_t)n * 512 + b * 64 + seg * 8;
        bf16x8 xv = *(const bf16x8*)(xg + go);
        bf16x8 t1 = *(const bf16x8*)(Tx1g + go);
        bf16x8 t2 = *(const bf16x8*)(Tx2g + go);
        *(bf16x8*)&buf[r * 264 + seg * 8] = xv;
        *(bf16x8*)&buf[r * 264 + 64 + seg * 8] = t1;
        *(bf16x8*)&buf[r * 264 + 128 + seg * 8] = t2;
    }
    __syncthreads();

    float sp = logf(1.f + expf(beta[0]));
    int lane = t & 63, w = t >> 6;
    int m = lane & 15, quad = lane >> 4;
    int q8 = quad * 8;

    // ---- GEMM1: h = A0[64x192] @ Wc[192x256], +bc, swish (regs -> buf)
    {
        f32x4 acc[4][2] = {};
        bf16x8 bfr[4][2];   // rolling 4-deep B pipeline, 2 col-tiles
        bf16x8 afr[2][4];   // A double-buffer, all 4 m-tiles
        const u16* Wp = Wct + (w * 32 + m) * 192 + q8;
#pragma unroll
        for (int d = 0; d < 4; ++d)
#pragma unroll
            for (int nt = 0; nt < 2; ++nt)
                bfr[d][nt] = *(const bf16x8*)(Wp + nt * 16 * 192 + d * 32);
#pragma unroll
        for (int r = 0; r < 4; ++r)
            afr[0][r] = *(const bf16x8*)&buf[(r * 16 + m) * 264 + q8];
#pragma unroll
        for (int kc = 0; kc < 6; ++kc) {
            if (kc < 5) {
                int koff2 = (kc + 1) * 32 + q8;
#pragma unroll
                for (int r = 0; r < 4; ++r)
                    afr[(kc + 1) & 1][r] = *(const bf16x8*)&buf[(r * 16 + m) * 264 + koff2];
            }
#pragma unroll
            for (int nt = 0; nt < 2; ++nt) {
                acc[0][nt] = MFMA16(afr[kc & 1][0], bfr[kc & 3][nt], acc[0][nt]);
                acc[1][nt] = MFMA16(afr[kc & 1][1], bfr[kc & 3][nt], acc[1][nt]);
                acc[2][nt] = MFMA16(afr[kc & 1][2], bfr[kc & 3][nt], acc[2][nt]);
                acc[3][nt] = MFMA16(afr[kc & 1][3], bfr[kc & 3][nt], acc[3][nt]);
            }
            if (kc + 4 < 6) {
#pragma unroll
                for (int nt = 0; nt < 2; ++nt)
                    bfr[kc & 3][nt] = *(const bf16x8*)(Wp + nt * 16 * 192 + (kc + 4) * 32);
            }
        }
        __syncthreads();   // all waves done reading A0; safe to overwrite
#pragma unroll
        for (int mt = 0; mt < 4; ++mt)
#pragma unroll
            for (int nt = 0; nt < 2; ++nt) {
                int col = w * 32 + nt * 16 + m;
                float bcv = bc[col];
#pragma unroll
                for (int i = 0; i < 4; ++i) {
                    int row = mt * 16 + quad * 4 + i;
                    buf[row * 264 + col] = f2bf(swish_f(acc[mt][nt][i] + bcv, sp));
                }
            }
    }
    __syncthreads();

    // ---- GEMM2: h2 = A1[64x256] @ W1[256x256], +b1, swish (regs -> buf)
    {
        f32x4 acc[4][2] = {};
        bf16x8 bfr[4][2];
        bf16x8 afr[2][4];
        const u16* Wp = W1t + (w * 32 + m) * 256 + q8;
#pragma unroll
        for (int d = 0; d < 4; ++d)
#pragma unroll
            for (int nt = 0; nt < 2; ++nt)
                bfr[d][nt] = *(const bf16x8*)(Wp + nt * 16 * 256 + d * 32);
#pragma unroll
        for (int r = 0; r < 4; ++r)
            afr[0][r] = *(const bf16x8*)&buf[(r * 16 + m) * 264 + q8];
#pragma unroll
        for (int kc = 0; kc < 8; ++kc) {
            if (kc < 7) {
                int koff2 = (kc + 1) * 32 + q8;
#pragma unroll
                for (int r = 0; r < 4; ++r)
                    afr[(kc + 1) & 1][r] = *(const bf16x8*)&buf[(r * 16 + m) * 264 + koff2];
            }
#pragma unroll
            for (int nt = 0; nt < 2; ++nt) {
                acc[0][nt] = MFMA16(afr[kc & 1][0], bfr[kc & 3][nt], acc[0][nt]);
                acc[1][nt] = MFMA16(afr[kc & 1][1], bfr[kc & 3][nt], acc[1][nt]);
                acc[2][nt] = MFMA16(afr[kc & 1][2], bfr[kc & 3][nt], acc[2][nt]);
                acc[3][nt] = MFMA16(afr[kc & 1][3], bfr[kc & 3][nt], acc[3][nt]);
            }
            if (kc + 4 < 8) {
#pragma unroll
                for (int nt = 0; nt < 2; ++nt)
                    bfr[kc & 3][nt] = *(const bf16x8*)(Wp + nt * 16 * 256 + (kc + 4) * 32);
            }
        }
        __syncthreads();   // all waves done reading h; safe to overwrite
#pragma unroll
        for (int mt = 0; mt < 4; ++mt)
#pragma unroll
            for (int nt = 0; nt < 2; ++nt) {
                int col = w * 32 + nt * 16 + m;
                float b1v = b1[col];
#pragma unroll
                for (int i = 0; i < 4; ++i) {
                    int row = mt * 16 + quad * 4 + i;
                    buf[row * 264 + col] = f2bf(swish_f(acc[mt][nt][i] + b1v, sp));
                }
            }
    }
    __syncthreads();

    // ---- GEMM3: Fx = A2[64x256] @ W2[256x64], +b2; out = Fx + x, Fx
    // wave (wm3 = w>>2, wn3 = w&3): rows wm3*32..+32, cols wn3*16..+16
    {
        int wm3 = w >> 2, wn3 = w & 3;
        int rb3 = wm3 * 32;
        f32x4 acc3[2] = {};
        bf16x8 bfr[8];      // whole B panel preloaded (8 x 16B = 32 VGPR)
        bf16x8 afr[2][2];
        const u16* Wp = W2t + (wn3 * 16 + m) * 256 + q8;
#pragma unroll
        for (int d = 0; d < 8; ++d) bfr[d] = *(const bf16x8*)(Wp + d * 32);
#pragma unroll
        for (int r = 0; r < 2; ++r)
            afr[0][r] = *(const bf16x8*)&buf[(rb3 + r * 16 + m) * 264 + q8];
#pragma unroll
        for (int kc = 0; kc < 8; ++kc) {
            if (kc < 7) {
                int koff2 = (kc + 1) * 32 + q8;
#pragma unroll
                for (int r = 0; r < 2; ++r)
                    afr[(kc + 1) & 1][r] = *(const bf16x8*)&buf[(rb3 + r * 16 + m) * 264 + koff2];
            }
            acc3[0] = MFMA16(afr[kc & 1][0], bfr[kc], acc3[0]);
            acc3[1] = MFMA16(afr[kc & 1][1], bfr[kc], acc3[1]);
        }
        int col = wn3 * 16 + m;
        float b2v = b2[col];
#pragma unroll
        for (int mt = 0; mt < 2; ++mt)
#pragma unroll
            for (int i = 0; i < 4; ++i) {
                int row = rb3 + mt * 16 + quad * 4 + i;
                size_t g = ((size_t)blockIdx.x * 64 + row) * 64 + col;
                float f = acc3[mt][i] + b2v;
                out[g] = f + x[g];
                out[OUT_OFF_ + g] = f;
            }
    }
}

extern "C" void kernel_launch(void* const* d_in, const int* in_sizes, int n_in,
                              void* d_out, int out_size, void* d_ws, size_t ws_size,
                              hipStream_t stream) {
    const float* x    = (const float*)d_in[0];
    const float* ew   = (const float*)d_in[1];
    const float* Wc   = (const float*)d_in[2];
    const float* bc   = (const float*)d_in[3];
    const float* W1   = (const float*)d_in[4];
    const float* b1   = (const float*)d_in[5];
    const float* W2   = (const float*)d_in[6];
    const float* b2   = (const float*)d_in[7];
    const float* beta = (const float*)d_in[8];
    const int*   ei   = (const int*)d_in[9];
    const int* src = ei;
    const int* dst = ei + E_;
    float* out = (float*)d_out;

    // workspace layout (float units)
    float* ws = (float*)d_ws;
    float* deg    = ws + 0;                 // N
    float* dis    = ws + 10000;             // N
    int*   cnt    = (int*)(ws + 20000);     // N
    int*   offs   = (int*)(ws + 30000);     // N+1 (pad to 10008)
    int*   cursor = (int*)(ws + 40008);     // N
    int*   ssrc   = (int*)(ws + 50008);     // E
    float* sw     = ws + 210008;            // E
    u16*   xg     = (u16*)(ws + 370008);    // [n][b][c] B*N*C u16
    u16*   Tx1g   = (u16*)(ws + 2930008);   // [n][b][c] B*N*C u16
    u16*   Tx2g   = (u16*)(ws + 5490008);   // [n][b][c] B*N*C u16
    u16*   Wct    = (u16*)(ws + 8050008);   // 49152 u16
    u16*   W1t    = (u16*)(ws + 8074584);   // 65536 u16
    u16*   W2t    = (u16*)(ws + 8107352);   // 16384 u16

    hipMemsetAsync(deg, 0, (size_t)N_ * sizeof(float), stream);
    hipMemsetAsync(cnt, 0, (size_t)N_ * sizeof(int), stream);

    k_deg<<<(E_ + 255) / 256, 256, 0, stream>>>(dst, ew, deg, cnt);
    k_dis<<<(N_ + 255) / 256, 256, 0, stream>>>(deg, dis);
    k_scan<<<1, 1024, 0, stream>>>(cnt, offs, cursor);
    k_scatter<<<(E_ + 255) / 256, 256, 0, stream>>>(src, dst, ew, dis, cursor, ssrc, sw);
    k_prepw<<<(131072 + (B_ * N_ * C_) / 4 + 255) / 256, 256, 0, stream>>>(
        Wc, W1, W2, x, Wct, W1t, W2t, xg);
    k_prop_g<<<N_ / 4, 256, 0, stream>>>(xg, offs, ssrc, sw, xg, Tx1g, 0);
    k_prop_g<<<N_ / 4, 256, 0, stream>>>(Tx1g, offs, ssrc, sw, xg, Tx2g, 1);
    k_fused<<<ROWS_ / 64, 512, 0, stream>>>(x, xg, Tx1g, Tx2g, Wct, bc, W1t, b1,
                                            W2t, b2, beta, out);
}

// Round 9
// 241.667 us; speedup vs baseline: 1.1555x; 1.0077x over previous
//
#include <hip/hip_runtime.h>
#include <cstdint>
#include <cstddef>

#define B_ 8
#define N_ 10000
#define C_ 64
#define DIM_ 256
#define E_ 160000
#define ROWS_ (B_ * N_)            // 80000
#define OUT_OFF_ ((size_t)B_ * N_ * C_)  // 5,120,000

typedef unsigned short u16;
typedef unsigned int u32;
typedef __attribute__((ext_vector_type(8))) short bf16x8;
typedef __attribute__((ext_vector_type(4))) float f32x4;

__device__ __forceinline__ u16 f2bf(float f) {
    unsigned int u = __float_as_uint(f);
    unsigned int r = u + 0x7FFF + ((u >> 16) & 1);  // RNE
    return (u16)(r >> 16);
}
__device__ __forceinline__ float bf2f(u32 h) {      // low 16 bits hold bf16
    return __uint_as_float(h << 16);
}
__device__ __forceinline__ unsigned int pack2(float a, float b) {
    return (unsigned int)f2bf(a) | ((unsigned int)f2bf(b) << 16);
}
__device__ __forceinline__ float swish_f(float v, float sp) {
    float e = __expf(-v * sp);
    float s = __builtin_amdgcn_rcpf(1.0f + e);
    return v * s * (1.0f / 1.1f);
}

#define MFMA16(a, b, c) __builtin_amdgcn_mfma_f32_16x16x32_bf16(a, b, c, 0, 0, 0)

// ---- graph preprocessing -------------------------------------------------

__global__ void k_deg(const int* __restrict__ dst, const float* __restrict__ ew,
                      float* __restrict__ deg, int* __restrict__ cnt) {
    int e = blockIdx.x * 256 + threadIdx.x;
    if (e < E_) {
        int d = dst[e];
        atomicAdd(&deg[d], ew[e]);
        atomicAdd(&cnt[d], 1);
    }
}

// R9: scan + dis fused (dis was a separate 1-µs launch; its input deg is
// already resident here). Single 1024-thread block, CH=10 elems/thread.
__global__ void k_scan(const int* __restrict__ cnt, const float* __restrict__ deg,
                       int* __restrict__ offs, int* __restrict__ cursor,
                       float* __restrict__ dis) {
    __shared__ int part[1024];
    int t = threadIdx.x;
    const int CH = 10;
    int base = t * CH;
    int s = 0;
    for (int i = 0; i < CH; i++) {
        int idx = base + i;
        if (idx < N_) s += cnt[idx];
    }
    part[t] = s;
    __syncthreads();
    for (int off = 1; off < 1024; off <<= 1) {
        int v = 0;
        if (t >= off) v = part[t - off];
        __syncthreads();
        if (t >= off) part[t] += v;
        __syncthreads();
    }
    int run = (t > 0) ? part[t - 1] : 0;
    for (int i = 0; i < CH; i++) {
        int idx = base + i;
        if (idx < N_) {
            offs[idx] = run;
            cursor[idx] = run;
            run += cnt[idx];
            float d = deg[idx];
            dis[idx] = d > 0.f ? rsqrtf(d) : 0.f;
        }
    }
    if (t == 1023) offs[N_] = run;
}

// R9: scatter + weight-prep merged into one launch (independent work, both
// ready once scan/dis completes; block-range split).
#define SCAT_BLKS_ ((E_ + 255) / 256)              // 625
__global__ void k_sp(const int* __restrict__ src, const int* __restrict__ dst,
                     const float* __restrict__ ew, const float* __restrict__ dis,
                     int* __restrict__ cursor, int* __restrict__ ssrc,
                     float* __restrict__ sw,
                     const float* __restrict__ Wc, const float* __restrict__ W1,
                     const float* __restrict__ W2, const float* __restrict__ x,
                     u16* __restrict__ Wct, u16* __restrict__ W1t,
                     u16* __restrict__ W2t, u16* __restrict__ xg) {
    if (blockIdx.x < SCAT_BLKS_) {
        int e = blockIdx.x * 256 + threadIdx.x;
        if (e < E_) {
            int sn = src[e], dn = dst[e];
            float w = -(dis[sn] * ew[e] * dis[dn]);
            int p = atomicAdd(&cursor[dn], 1);
            ssrc[p] = sn;
            sw[p] = w;
        }
        return;
    }
    int i = (blockIdx.x - SCAT_BLKS_) * 256 + threadIdx.x;
    if (i < 49152) {
        int nr = i / 192, k = i % 192;
        Wct[i] = f2bf(Wc[k * 256 + nr]);
    } else if (i < 114688) {
        int j = i - 49152;
        int nr = j >> 8, k = j & 255;
        W1t[j] = f2bf(W1[k * 256 + nr]);
    } else if (i < 131072) {
        int j = i - 114688;
        int nr = j >> 8, k = j & 255;
        W2t[j] = f2bf(W2[k * 64 + nr]);
    } else {
        int j = i - 131072;
        if (j < (B_ * N_ * C_) / 4) {
            float4 v = ((const float4*)x)[j];
            int flat4 = j * 4;                 // [b][n][c] flat f32 index
            int b = flat4 / (N_ * C_);
            int rem = flat4 - b * (N_ * C_);
            int n = rem >> 6, c = rem & 63;
            uint2 pv = {pack2(v.x, v.y), pack2(v.z, v.w)};
            *(uint2*)(xg + (size_t)n * 512 + b * 64 + c) = pv;
        }
    }
}

// Batch-merged gather SpMM (R7/R8): one wave per NODE; per edge one
// contiguous 1 KB row (8 batches x 64 ch), 8-deep edge pipeline.
// Lane l owns (b=l>>3, c=(l&7)*8..+8). mode==1: O = 2*sum - xg_row.
__global__ __launch_bounds__(256) void k_prop_g(
        const u16* __restrict__ Tg, const int* __restrict__ offs,
        const int* __restrict__ ssrc, const float* __restrict__ sw,
        const u16* __restrict__ xg, u16* __restrict__ Og, int mode) {
    int w = __builtin_amdgcn_readfirstlane(threadIdx.x >> 6);
    int lane = threadIdx.x & 63;
    int n = blockIdx.x * 4 + w;
    int s = offs[n], e = offs[n + 1];
    int lo = lane * 8;
    float sum[8] = {};
    int j = s;
    for (; j < e && (j & 3); ++j) {
        int idx = ssrc[j];
        float wv = sw[j];
        bf16x8 v = *(const bf16x8*)(Tg + (size_t)idx * 512 + lo);
#pragma unroll
        for (int k = 0; k < 8; ++k) sum[k] += bf2f((u16)v[k]) * wv;
    }
    for (; j + 8 <= e; j += 8) {
        int4 ia = *(const int4*)&ssrc[j];
        int4 ib = *(const int4*)&ssrc[j + 4];
        float4 wa = *(const float4*)&sw[j];
        float4 wb = *(const float4*)&sw[j + 4];
        bf16x8 v0 = *(const bf16x8*)(Tg + (size_t)ia.x * 512 + lo);
        bf16x8 v1 = *(const bf16x8*)(Tg + (size_t)ia.y * 512 + lo);
        bf16x8 v2 = *(const bf16x8*)(Tg + (size_t)ia.z * 512 + lo);
        bf16x8 v3 = *(const bf16x8*)(Tg + (size_t)ia.w * 512 + lo);
        bf16x8 v4 = *(const bf16x8*)(Tg + (size_t)ib.x * 512 + lo);
        bf16x8 v5 = *(const bf16x8*)(Tg + (size_t)ib.y * 512 + lo);
        bf16x8 v6 = *(const bf16x8*)(Tg + (size_t)ib.z * 512 + lo);
        bf16x8 v7 = *(const bf16x8*)(Tg + (size_t)ib.w * 512 + lo);
#pragma unroll
        for (int k = 0; k < 8; ++k)
            sum[k] += bf2f((u16)v0[k]) * wa.x + bf2f((u16)v1[k]) * wa.y
                    + bf2f((u16)v2[k]) * wa.z + bf2f((u16)v3[k]) * wa.w
                    + bf2f((u16)v4[k]) * wb.x + bf2f((u16)v5[k]) * wb.y
                    + bf2f((u16)v6[k]) * wb.z + bf2f((u16)v7[k]) * wb.w;
    }
    for (; j + 4 <= e; j += 4) {
        int4 idx = *(const int4*)&ssrc[j];
        float4 wv = *(const float4*)&sw[j];
        bf16x8 v0 = *(const bf16x8*)(Tg + (size_t)idx.x * 512 + lo);
        bf16x8 v1 = *(const bf16x8*)(Tg + (size_t)idx.y * 512 + lo);
        bf16x8 v2 = *(const bf16x8*)(Tg + (size_t)idx.z * 512 + lo);
        bf16x8 v3 = *(const bf16x8*)(Tg + (size_t)idx.w * 512 + lo);
#pragma unroll
        for (int k = 0; k < 8; ++k)
            sum[k] += bf2f((u16)v0[k]) * wv.x + bf2f((u16)v1[k]) * wv.y
                    + bf2f((u16)v2[k]) * wv.z + bf2f((u16)v3[k]) * wv.w;
    }
    for (; j < e; ++j) {
        int idx = ssrc[j];
        float wv = sw[j];
        bf16x8 v = *(const bf16x8*)(Tg + (size_t)idx * 512 + lo);
#pragma unroll
        for (int k = 0; k < 8; ++k) sum[k] += bf2f((u16)v[k]) * wv;
    }
    size_t go = (size_t)n * 512 + lo;
    bf16x8 o;
    if (mode == 1) {
        bf16x8 xv = *(const bf16x8*)(xg + go);
#pragma unroll
        for (int k = 0; k < 8; ++k) o[k] = (short)f2bf(2.f * sum[k] - bf2f((u16)xv[k]));
    } else {
#pragma unroll
        for (int k = 0; k < 8; ++k) o[k] = (short)f2bf(sum[k]);
    }
    *(bf16x8*)(Og + go) = o;
}

// ---- fused cheb-einsum + MLP, bf16 MFMA, M=64 rows/block -----------------
// R6/R8 structure. R9 change: __launch_bounds__(512, 6) -> 6 waves/EU =
// 3 blocks/CU. Unified-register arithmetic (R5 lesson): arch 48 + acc 32 =
// 80 total <= 512/6 = 85/wave tier; allocator cap 85-32=53 arch vs 48 used
// -> no squeeze, no spill (unlike R3's impossible 64). LDS 3 x 33.8 = 101 KB.
__global__ __launch_bounds__(512, 6) void k_fused(
        const float* __restrict__ x, const u16* __restrict__ xg,
        const u16* __restrict__ Tx1g, const u16* __restrict__ Tx2g,
        const u16* __restrict__ Wct, const float* __restrict__ bc,
        const u16* __restrict__ W1t, const float* __restrict__ b1,
        const u16* __restrict__ W2t, const float* __restrict__ b2,
        const float* __restrict__ beta, float* __restrict__ out) {
    __shared__ u16 buf[64 * 264];   // A0 (cols 0..191) -> h (0..255) -> h2
    int t = threadIdx.x;

    // stage A0 = [xg | Tx1g | Tx2g] bf16, row-major, K-stride 264
    {
        int r = t >> 3, seg = t & 7;            // 64 rows x 8 segs of 16 B
        size_t g = (size_t)blockIdx.x * 64 + r;
        int b = (int)(g / N_), n = (int)(g % N_);
        size_t go = (size_t)n * 512 + b * 64 + seg * 8;
        bf16x8 xv = *(const bf16x8*)(xg + go);
        bf16x8 t1 = *(const bf16x8*)(Tx1g + go);
        bf16x8 t2 = *(const bf16x8*)(Tx2g + go);
        *(bf16x8*)&buf[r * 264 + seg * 8] = xv;
        *(bf16x8*)&buf[r * 264 + 64 + seg * 8] = t1;
        *(bf16x8*)&buf[r * 264 + 128 + seg * 8] = t2;
    }
    __syncthreads();

    float sp = logf(1.f + expf(beta[0]));
    int lane = t & 63, w = t >> 6;
    int m = lane & 15, quad = lane >> 4;
    int q8 = quad * 8;

    // ---- GEMM1: h = A0[64x192] @ Wc[192x256], +bc, swish (regs -> buf)
    {
        f32x4 acc[4][2] = {};
        bf16x8 bfr[4][2];   // rolling 4-deep B pipeline, 2 col-tiles
        bf16x8 afr[2][4];   // A double-buffer, all 4 m-tiles
        const u16* Wp = Wct + (w * 32 + m) * 192 + q8;
#pragma unroll
        for (int d = 0; d < 4; ++d)
#pragma unroll
            for (int nt = 0; nt < 2; ++nt)
                bfr[d][nt] = *(const bf16x8*)(Wp + nt * 16 * 192 + d * 32);
#pragma unroll
        for (int r = 0; r < 4; ++r)
            afr[0][r] = *(const bf16x8*)&buf[(r * 16 + m) * 264 + q8];
#pragma unroll
        for (int kc = 0; kc < 6; ++kc) {
            if (kc < 5) {
                int koff2 = (kc + 1) * 32 + q8;
#pragma unroll
                for (int r = 0; r < 4; ++r)
                    afr[(kc + 1) & 1][r] = *(const bf16x8*)&buf[(r * 16 + m) * 264 + koff2];
            }
#pragma unroll
            for (int nt = 0; nt < 2; ++nt) {
                acc[0][nt] = MFMA16(afr[kc & 1][0], bfr[kc & 3][nt], acc[0][nt]);
                acc[1][nt] = MFMA16(afr[kc & 1][1], bfr[kc & 3][nt], acc[1][nt]);
                acc[2][nt] = MFMA16(afr[kc & 1][2], bfr[kc & 3][nt], acc[2][nt]);
                acc[3][nt] = MFMA16(afr[kc & 1][3], bfr[kc & 3][nt], acc[3][nt]);
            }
            if (kc + 4 < 6) {
#pragma unroll
                for (int nt = 0; nt < 2; ++nt)
                    bfr[kc & 3][nt] = *(const bf16x8*)(Wp + nt * 16 * 192 + (kc + 4) * 32);
            }
        }
        __syncthreads();   // all waves done reading A0; safe to overwrite
#pragma unroll
        for (int mt = 0; mt < 4; ++mt)
#pragma unroll
            for (int nt = 0; nt < 2; ++nt) {
                int col = w * 32 + nt * 16 + m;
                float bcv = bc[col];
#pragma unroll
                for (int i = 0; i < 4; ++i) {
                    int row = mt * 16 + quad * 4 + i;
                    buf[row * 264 + col] = f2bf(swish_f(acc[mt][nt][i] + bcv, sp));
                }
            }
    }
    __syncthreads();

    // ---- GEMM2: h2 = A1[64x256] @ W1[256x256], +b1, swish (regs -> buf)
    {
        f32x4 acc[4][2] = {};
        bf16x8 bfr[4][2];
        bf16x8 afr[2][4];
        const u16* Wp = W1t + (w * 32 + m) * 256 + q8;
#pragma unroll
        for (int d = 0; d < 4; ++d)
#pragma unroll
            for (int nt = 0; nt < 2; ++nt)
                bfr[d][nt] = *(const bf16x8*)(Wp + nt * 16 * 256 + d * 32);
#pragma unroll
        for (int r = 0; r < 4; ++r)
            afr[0][r] = *(const bf16x8*)&buf[(r * 16 + m) * 264 + q8];
#pragma unroll
        for (int kc = 0; kc < 8; ++kc) {
            if (kc < 7) {
                int koff2 = (kc + 1) * 32 + q8;
#pragma unroll
                for (int r = 0; r < 4; ++r)
                    afr[(kc + 1) & 1][r] = *(const bf16x8*)&buf[(r * 16 + m) * 264 + koff2];
            }
#pragma unroll
            for (int nt = 0; nt < 2; ++nt) {
                acc[0][nt] = MFMA16(afr[kc & 1][0], bfr[kc & 3][nt], acc[0][nt]);
                acc[1][nt] = MFMA16(afr[kc & 1][1], bfr[kc & 3][nt], acc[1][nt]);
                acc[2][nt] = MFMA16(afr[kc & 1][2], bfr[kc & 3][nt], acc[2][nt]);
                acc[3][nt] = MFMA16(afr[kc & 1][3], bfr[kc & 3][nt], acc[3][nt]);
            }
            if (kc + 4 < 8) {
#pragma unroll
                for (int nt = 0; nt < 2; ++nt)
                    bfr[kc & 3][nt] = *(const bf16x8*)(Wp + nt * 16 * 256 + (kc + 4) * 32);
            }
        }
        __syncthreads();   // all waves done reading h; safe to overwrite
#pragma unroll
        for (int mt = 0; mt < 4; ++mt)
#pragma unroll
            for (int nt = 0; nt < 2; ++nt) {
                int col = w * 32 + nt * 16 + m;
                float b1v = b1[col];
#pragma unroll
                for (int i = 0; i < 4; ++i) {
                    int row = mt * 16 + quad * 4 + i;
                    buf[row * 264 + col] = f2bf(swish_f(acc[mt][nt][i] + b1v, sp));
                }
            }
    }
    __syncthreads();

    // ---- GEMM3: Fx = A2[64x256] @ W2[256x64], +b2; out = Fx + x, Fx
    // wave (wm3 = w>>2, wn3 = w&3): rows wm3*32..+32, cols wn3*16..+16
    {
        int wm3 = w >> 2, wn3 = w & 3;
        int rb3 = wm3 * 32;
        f32x4 acc3[2] = {};
        bf16x8 bfr[8];      // whole B panel preloaded (8 x 16B = 32 VGPR)
        bf16x8 afr[2][2];
        const u16* Wp = W2t + (wn3 * 16 + m) * 256 + q8;
#pragma unroll
        for (int d = 0; d < 8; ++d) bfr[d] = *(const bf16x8*)(Wp + d * 32);
#pragma unroll
        for (int r = 0; r < 2; ++r)
            afr[0][r] = *(const bf16x8*)&buf[(rb3 + r * 16 + m) * 264 + q8];
#pragma unroll
        for (int kc = 0; kc < 8; ++kc) {
            if (kc < 7) {
                int koff2 = (kc + 1) * 32 + q8;
#pragma unroll
                for (int r = 0; r < 2; ++r)
                    afr[(kc + 1) & 1][r] = *(const bf16x8*)&buf[(rb3 + r * 16 + m) * 264 + koff2];
            }
            acc3[0] = MFMA16(afr[kc & 1][0], bfr[kc], acc3[0]);
            acc3[1] = MFMA16(afr[kc & 1][1], bfr[kc], acc3[1]);
        }
        int col = wn3 * 16 + m;
        float b2v = b2[col];
#pragma unroll
        for (int mt = 0; mt < 2; ++mt)
#pragma unroll
            for (int i = 0; i < 4; ++i) {
                int row = rb3 + mt * 16 + quad * 4 + i;
                size_t g = ((size_t)blockIdx.x * 64 + row) * 64 + col;
                float f = acc3[mt][i] + b2v;
                out[g] = f + x[g];
                out[OUT_OFF_ + g] = f;
            }
    }
}

extern "C" void kernel_launch(void* const* d_in, const int* in_sizes, int n_in,
                              void* d_out, int out_size, void* d_ws, size_t ws_size,
                              hipStream_t stream) {
    const float* x    = (const float*)d_in[0];
    const float* ew   = (const float*)d_in[1];
    const float* Wc   = (const float*)d_in[2];
    const float* bc   = (const float*)d_in[3];
    const float* W1   = (const float*)d_in[4];
    const float* b1   = (const float*)d_in[5];
    const float* W2   = (const float*)d_in[6];
    const float* b2   = (const float*)d_in[7];
    const float* beta = (const float*)d_in[8];
    const int*   ei   = (const int*)d_in[9];
    const int* src = ei;
    const int* dst = ei + E_;
    float* out = (float*)d_out;

    // workspace layout (float units) — deg|cnt contiguous for single memset
    float* ws = (float*)d_ws;
    float* deg    = ws + 0;                 // N
    int*   cnt    = (int*)(ws + 10000);     // N  (contiguous with deg)
    float* dis    = ws + 20000;             // N
    int*   offs   = (int*)(ws + 30000);     // N+1 (pad to 10008)
    int*   cursor = (int*)(ws + 40008);     // N
    int*   ssrc   = (int*)(ws + 50008);     // E
    float* sw     = ws + 210008;            // E
    u16*   xg     = (u16*)(ws + 370008);    // [n][b][c] B*N*C u16
    u16*   Tx1g   = (u16*)(ws + 2930008);   // [n][b][c] B*N*C u16
    u16*   Tx2g   = (u16*)(ws + 5490008);   // [n][b][c] B*N*C u16
    u16*   Wct    = (u16*)(ws + 8050008);   // 49152 u16
    u16*   W1t    = (u16*)(ws + 8074584);   // 65536 u16
    u16*   W2t    = (u16*)(ws + 8107352);   // 16384 u16

    hipMemsetAsync(deg, 0, (size_t)2 * N_ * sizeof(float), stream);  // deg+cnt

    k_deg<<<(E_ + 255) / 256, 256, 0, stream>>>(dst, ew, deg, cnt);
    k_scan<<<1, 1024, 0, stream>>>(cnt, deg, offs, cursor, dis);
    k_sp<<<SCAT_BLKS_ + (131072 + (B_ * N_ * C_) / 4) / 256, 256, 0, stream>>>(
        src, dst, ew, dis, cursor, ssrc, sw, Wc, W1, W2, x, Wct, W1t, W2t, xg);
    k_prop_g<<<N_ / 4, 256, 0, stream>>>(xg, offs, ssrc, sw, xg, Tx1g, 0);
    k_prop_g<<<N_ / 4, 256, 0, stream>>>(Tx1g, offs, ssrc, sw, xg, Tx2g, 1);
    k_fused<<<ROWS_ / 64, 512, 0, stream>>>(x, xg, Tx1g, Tx2g, Wct, bc, W1t, b1,
                                            W2t, b2, beta, out);
}